// Round 4
// baseline (690.840 us; speedup 1.0000x reference)
//
#include <hip/hip_runtime.h>
#include <stdint.h>

#define B_    128
#define S_    256
#define EMB_  300
#define HID_  256
#define TAGS_ 50
#define KPAD  320           // EMB padded to multiple of 32
#define NROWS (B_ * S_)     // 32768, row r = s*128 + b
#define GF    (4 * HID_)    // 1024 gate cols per direction
#define NCOLS (2 * GF)      // 2048 (fwd | bwd)

typedef __bf16 bf16x8 __attribute__((ext_vector_type(8)));
typedef float  f32x4  __attribute__((ext_vector_type(4)));
typedef unsigned int u32x4 __attribute__((ext_vector_type(4)));
typedef int    i32x8  __attribute__((ext_vector_type(8)));

__device__ __forceinline__ unsigned short f2bf(float f) {
    unsigned int u = __float_as_uint(f);
    unsigned int r = (u + 0x7fffu + ((u >> 16) & 1u)) >> 16;  // RNE
    return (unsigned short)r;
}
__device__ __forceinline__ bf16x8 ldb8(const unsigned short* p) {
    u32x4 v = *reinterpret_cast<const u32x4*>(p);
    return __builtin_bit_cast(bf16x8, v);
}
// fast sigmoid: v_exp_f32 + v_rcp_f32 (no IEEE div expansion; ~1ulp rcp err)
__device__ __forceinline__ float sigf(float x) {
    return __builtin_amdgcn_rcpf(1.0f + __builtin_amdgcn_exp2f(x * -1.44269504f));
}
// 4-way select by q (2-level cndmask chain, no dynamic indexing)
__device__ __forceinline__ float sel4(float v0, float v1, float v2, float v3, int q) {
    float a = (q & 1) ? v1 : v0;
    float b = (q & 1) ? v3 : v2;
    return (q & 2) ? b : a;
}

// ---------------- K0a: embedding gather -> bf16, K-padded -------------------
__global__ void k_gather_x(const int* __restrict__ tokens, const float* __restrict__ emb,
                           unsigned short* __restrict__ X16) {
    int r = blockIdx.x;            // r = s*128 + b
    int k = threadIdx.x;           // 0..319
    int b = r & 127, s = r >> 7;
    int tok = tokens[b * S_ + s];
    float v = (k < EMB_) ? emb[(long)tok * EMB_ + k] : 0.0f;
    X16[(long)r * KPAD + k] = f2bf(v);
}

// ---------------- K0b: Wx (f|b) -> transposed bf16 [2048][320] --------------
__global__ void k_prep_w(const float* __restrict__ Wx_f, const float* __restrict__ Wx_b,
                         unsigned short* __restrict__ W16T) {
    int c = blockIdx.x;            // 0..2047
    int k = threadIdx.x;           // 0..319
    float v = 0.0f;
    if (k < EMB_) v = (c < GF) ? Wx_f[k * GF + c] : Wx_b[k * GF + (c - GF)];
    W16T[c * KPAD + k] = f2bf(v);
}

// ---------------- K0c: Wd -> transposed bf16 [64][512] ----------------------
__global__ void k_prep_wd(const float* __restrict__ Wd, unsigned short* __restrict__ WdT16) {
    int c = blockIdx.x;            // 0..63
    int k = threadIdx.x;           // 0..511
    float v = (c < TAGS_) ? Wd[k * TAGS_ + c] : 0.0f;
    WdT16[c * 512 + k] = f2bf(v);
}

// ---------------- K0d: Wh -> packed bf16 [2 dir][4 sl][256 c][256 k] --------
__global__ void k_prep_wh(const float* __restrict__ Wh_f, const float* __restrict__ Wh_b,
                          unsigned short* __restrict__ WhP) {
    int row = blockIdx.x;          // 0..2047 = (d*4+sl)*256 + c
    int k = threadIdx.x;           // 0..255
    int d = row >> 10, sl = (row >> 8) & 3, c = row & 255;
    int gate = c >> 6, jrel = c & 63;
    const float* Wh = d ? Wh_b : Wh_f;
    WhP[(long)row * 256 + k] = f2bf(Wh[k * GF + gate * HID_ + sl * 64 + jrel]);
}

// ---------------- K0e: Wh gates i,f,o -> fp8 e4m3 [2 dir][3 g][256 j][256 k]-
__global__ void k_prep_wh8(const float* __restrict__ Wh_f, const float* __restrict__ Wh_b,
                           unsigned char* __restrict__ WhP8) {
    int row = blockIdx.x;          // 0..1535 = (d*3+gi)*256 + j
    int k = threadIdx.x;           // 0..255
    int d = row / 768, rr = row - d * 768, gi = rr >> 8, j = rr & 255;
    int ga = (gi == 2) ? 3 : gi;   // i=0, f=1, o=3
    const float* Wh = d ? Wh_b : Wh_f;
    float v = Wh[k * GF + ga * HID_ + j];
    int p = __builtin_amdgcn_cvt_pk_fp8_f32(v, 0.0f, 0, false);
    WhP8[(long)row * 256 + k] = (unsigned char)(p & 0xff);
}

// ---------------- K1: xz = X @ Wx + b  (MFMA, LDS-free) ---------------------
// xzP gate-major layout: u64 idx = ((s*16+g16)*64 + gate*16 + u16)*64 + b4*16 + j
// (u64 packs 4 batches b4*4+{0..3} as bf16). Producer stores are 512 B/wave
// contiguous; consumer reads are per-lane ushort picks (see K2).
__global__ __launch_bounds__(256) void k_gemm_xz(
    const unsigned short* __restrict__ X16, const unsigned short* __restrict__ W16T,
    const float* __restrict__ b_f, const float* __restrict__ b_b,
    unsigned long long* __restrict__ xzP) {
    int w = threadIdx.x >> 6, lane = threadIdx.x & 63;
    int quad = lane >> 4, l16 = lane & 15;
    int m0 = blockIdx.x * 128 + w * 32;
    int n0 = blockIdx.y * 128;
    f32x4 acc[2][8];
#pragma unroll
    for (int mt = 0; mt < 2; ++mt)
#pragma unroll
        for (int nt = 0; nt < 8; ++nt) acc[mt][nt] = (f32x4){0.f, 0.f, 0.f, 0.f};

    int koff = quad * 8;
#pragma unroll
    for (int ks = 0; ks < 10; ++ks) {
        int k0 = ks * 32 + koff;
        bf16x8 a[2], bb[8];
#pragma unroll
        for (int mt = 0; mt < 2; ++mt)
            a[mt] = ldb8(X16 + (long)(m0 + mt * 16 + l16) * KPAD + k0);
#pragma unroll
        for (int nt = 0; nt < 8; ++nt)
            bb[nt] = ldb8(W16T + (long)(n0 + nt * 16 + l16) * KPAD + k0);
#pragma unroll
        for (int mt = 0; mt < 2; ++mt)
#pragma unroll
            for (int nt = 0; nt < 8; ++nt)
                acc[mt][nt] = __builtin_amdgcn_mfma_f32_16x16x32_bf16(a[mt], bb[nt], acc[mt][nt], 0, 0, 0);
    }
    int s = blockIdx.x;            // m>>7
#pragma unroll
    for (int mt = 0; mt < 2; ++mt) {
        int grp = w * 2 + mt;      // (b>>4)
#pragma unroll
        for (int nt = 0; nt < 8; ++nt) {
            int col = n0 + nt * 16 + l16;
            int dir = col >> 10, cc = col & 1023;
            int gate = cc >> 8, u16 = (cc & 255) >> 4;
            float bias = dir ? b_b[cc] : b_f[cc];
            unsigned long long pk = 0;
#pragma unroll
            for (int r = 0; r < 4; ++r)
                pk |= (unsigned long long)f2bf(acc[mt][nt][r] + bias) << (16 * r);
            long idx8 = ((long)(s * 16 + dir * 8 + grp)) * 4096 +
                        (gate * 16 + u16) * 64 + quad * 16 + l16;
            xzP[idx8] = pk;
        }
    }
}

// ---------------- K2: bidirectional LSTM recurrence, single-CU chains -------
// Round-4 restructure: 256 blocks = 2 dir x 128 SINGLE batches, 256 threads
// (4 waves, 1 wave/SIMD). Rationale (rocprof r3): step = MFMA-issue(1449/SIMD,
// invariant to batching) + VALU(= waves/SIMD x cells/lane x ~425) in series.
// n_b=1 @ 256 thr gives 1 wave/SIMD x 1 cell/lane => VALU phase ~425 cyc.
// Bonus: all 16 A-rows are the same batch => every LDS A-read is a same-
// address 16-lane broadcast => bank conflicts ~0 (was 4.18M with rp parity).
// C element 0 of the cg=quad accumulator is the lane's cell (all rows equal).
// Wave pins 4 col-groups of B-fragments: 320 VGPR pinned (+64 acc) — watch
// VGPR_Count for spill. Block->(d,b) remap puts each b4-group's 4 blocks on
// one XCD (blk%8) so the shared 4-batch xzP cachelines hit L2, not HBM.
__global__ __launch_bounds__(256, 1) void k_recurrence(
    const unsigned short* __restrict__ WhP, const unsigned char* __restrict__ WhP8,
    const unsigned long long* __restrict__ xzP, unsigned short* __restrict__ hcat16) {
    __shared__ __align__(16) unsigned char lds[1536];
    const int HB = 0, H8 = 1024;   // hb: 2 x 512 B; h8: 2 x 256 B
    int tid = threadIdx.x;
    int w = tid >> 6, lane = tid & 63, quad = lane >> 4, l16 = lane & 15;
    // XCD-grouped bijective block->(d,b): x=blk&7 is the XCD; the 4 batches
    // of one b4-group all land on the same x.
    int blk = blockIdx.x;
    int x = blk & 7, t0 = blk >> 3;
    int j4 = t0 & 3, pslot = t0 >> 2;
    int pr = pslot * 8 + x;        // 0..63 = d*32 + g
    int d = pr >> 5, g = pr & 31;
    int b = 4 * g + j4;            // lane's batch (whole block shares it)

    int col = 64 * w + 16 * quad + l16;   // lane's cell column (0..255)

    // g-gate bf16 weight fragments, register-pinned [4 cg][8 kt] (128 VGPR)
    u32x4 whg[4][8];
#pragma unroll
    for (int cgi = 0; cgi < 4; ++cgi) {
        int j = 64 * w + 16 * cgi + l16;
        int sl = j >> 6, jrel = j & 63;
        const unsigned short* src = WhP + ((long)((d * 4 + sl) * 256 + 128 + jrel)) * 256;
#pragma unroll
        for (int kt = 0; kt < 8; ++kt) {
            u32x4 v = *reinterpret_cast<const u32x4*>(src + kt * 32 + quad * 8);
            asm volatile("" : "+v"(v));
            whg[cgi][kt] = v;
        }
    }
    // i/f/o fp8 K=128 scaled-MFMA B fragments, register-pinned [3][4][2] (192 VGPR)
    i32x8 wh8s[3][4][2];
#pragma unroll
    for (int gi = 0; gi < 3; ++gi)
#pragma unroll
        for (int cgi = 0; cgi < 4; ++cgi)
#pragma unroll
            for (int kt2 = 0; kt2 < 2; ++kt2) {
                const unsigned char* wp8 = WhP8 +
                    ((long)((d * 3 + gi) * 256 + 64 * w + 16 * cgi + l16)) * 256 +
                    kt2 * 128 + quad * 32;
                i32x8 v = *reinterpret_cast<const i32x8*>(wp8);
                asm volatile("" : "+v"(v));
                wh8s[gi][cgi][kt2] = v;
            }

    float c2 = 0.f;

    // xz addressing (u16 view of K1's u64 layout):
    // u16addr = (s*16+g16)*16384 + gate*4096 + laneoff0
    const unsigned short* xzU = (const unsigned short*)xzP;
    int g16 = d * 8 + (b >> 4);
    unsigned int laneoff0 = (unsigned)((((4 * w + quad) * 64) + ((b >> 2) & 3) * 16 + l16) * 4 + (b & 3));

    // preload xz for first step (4 ushorts per lane: gates i,f,g,o)
    unsigned short xzu[4];
    {
        int s0 = d ? 255 : 0;
        const unsigned short* ps = xzU + (unsigned long)(s0 * 16 + g16) * 16384;
#pragma unroll
        for (int ga = 0; ga < 4; ++ga) xzu[ga] = ps[laneoff0 + ga * 4096];
    }

    for (int t = 0; t < 256; ++t) {
        int s = d ? (255 - t) : t;
        int pb = t & 1, cb = pb ^ 1;
        f32x4 accg[4];
        f32x4 acc8[3][4];
#pragma unroll
        for (int cgi = 0; cgi < 4; ++cgi) {
            accg[cgi] = (f32x4){0.f, 0.f, 0.f, 0.f};
#pragma unroll
            for (int gi = 0; gi < 3; ++gi) acc8[gi][cgi] = (f32x4){0.f, 0.f, 0.f, 0.f};
        }

        if (t > 0) {
#pragma unroll
            for (int kt = 0; kt < 8; ++kt) {
                // all A rows = same batch -> same-address 16-lane broadcast
                bf16x8 A = ldb8(reinterpret_cast<const unsigned short*>(
                    lds + HB + cb * 512 + kt * 64 + quad * 16));
#pragma unroll
                for (int cgi = 0; cgi < 4; ++cgi)
                    accg[cgi] = __builtin_amdgcn_mfma_f32_16x16x32_bf16(
                        A, __builtin_bit_cast(bf16x8, whg[cgi][kt]), accg[cgi], 0, 0, 0);
            }
#pragma unroll
            for (int kt2 = 0; kt2 < 2; ++kt2) {
                i32x8 A8 = *reinterpret_cast<const i32x8*>(
                    lds + H8 + cb * 256 + kt2 * 128 + quad * 32);
#pragma unroll
                for (int cgi = 0; cgi < 4; ++cgi)
#pragma unroll
                    for (int gi = 0; gi < 3; ++gi)
#if __has_builtin(__builtin_amdgcn_mfma_scale_f32_16x16x128_f8f6f4)
                        acc8[gi][cgi] = __builtin_amdgcn_mfma_scale_f32_16x16x128_f8f6f4(
                            A8, wh8s[gi][cgi][kt2], acc8[gi][cgi], 0, 0, 0, 0x7F, 0, 0x7F);
#else
                        acc8[gi][cgi] = acc8[gi][cgi];  // unreachable on gfx950
#endif
            }
        }
        // extract current-step xz addends (bf16 -> f32 is one shl each)
        float xa0 = __uint_as_float((unsigned int)xzu[0] << 16);
        float xa1 = __uint_as_float((unsigned int)xzu[1] << 16);
        float xa2 = __uint_as_float((unsigned int)xzu[2] << 16);
        float xa3 = __uint_as_float((unsigned int)xzu[3] << 16);
        // prefetch next step (fire-and-forget; consumed after next barrier)
        {
            int sn = d ? (s ? s - 1 : 0) : (s < 255 ? s + 1 : 255);
            const unsigned short* ps = xzU + (unsigned long)(sn * 16 + g16) * 16384;
#pragma unroll
            for (int ga = 0; ga < 4; ++ga) xzu[ga] = ps[laneoff0 + ga * 4096];
        }
        // gates: lane's cell = (batch b, col). All C rows equal (replicated
        // batch) -> element 0; col-group select by quad (3 cndmask per gate).
        float zi = sel4(acc8[0][0][0], acc8[0][1][0], acc8[0][2][0], acc8[0][3][0], quad) + xa0;
        float zf = sel4(acc8[1][0][0], acc8[1][1][0], acc8[1][2][0], acc8[1][3][0], quad) + xa1;
        float zg = sel4(accg[0][0],    accg[1][0],    accg[2][0],    accg[3][0],    quad) + xa2;
        float zo = sel4(acc8[2][0][0], acc8[2][1][0], acc8[2][2][0], acc8[2][3][0], quad) + xa3;
        float c = sigf(zf) * c2 + sigf(zi) * fmaxf(zg, 0.0f);
        c2 = c;
        float h = sigf(zo) * fmaxf(c, 0.0f);

        unsigned short hb16 = f2bf(h);
        *reinterpret_cast<unsigned short*>(lds + HB + pb * 512 + col * 2) = hb16;
        int p8 = __builtin_amdgcn_cvt_pk_fp8_f32(h, h, 0, false);
        *(lds + H8 + pb * 256 + col) = (unsigned char)(p8 & 0xff);
        // hcat direct from register (fire-and-forget; barrier won't drain it)
        hcat16[((long)b * S_ + s) * 512 + d * HID_ + col] = hb16;
        // LDS-only barrier: no vmcnt drain (global stores/loads stay in flight)
        asm volatile("s_waitcnt lgkmcnt(0)\n\ts_barrier" ::: "memory");
    }
}

// ---------------- K3: logits = hcat @ Wd  (MFMA, N padded to 64) ------------
__global__ __launch_bounds__(256) void k_gemm_logits(
    const unsigned short* __restrict__ hcat16, const unsigned short* __restrict__ WdT16,
    float* __restrict__ logits) {
    int w = threadIdx.x >> 6, lane = threadIdx.x & 63;
    int quad = lane >> 4, l16 = lane & 15;
    int m0 = blockIdx.x * 128 + w * 32;
    f32x4 acc[2][4];
#pragma unroll
    for (int mt = 0; mt < 2; ++mt)
#pragma unroll
        for (int nt = 0; nt < 4; ++nt) acc[mt][nt] = (f32x4){0.f, 0.f, 0.f, 0.f};
#pragma unroll
    for (int ks = 0; ks < 16; ++ks) {
        int k0 = ks * 32 + quad * 8;
        bf16x8 a[2], bb[4];
#pragma unroll
        for (int mt = 0; mt < 2; ++mt)
            a[mt] = ldb8(hcat16 + (long)(m0 + mt * 16 + l16) * 512 + k0);
#pragma unroll
        for (int nt = 0; nt < 4; ++nt)
            bb[nt] = ldb8(WdT16 + (long)(nt * 16 + l16) * 512 + k0);
#pragma unroll
        for (int mt = 0; mt < 2; ++mt)
#pragma unroll
            for (int nt = 0; nt < 4; ++nt)
                acc[mt][nt] = __builtin_amdgcn_mfma_f32_16x16x32_bf16(a[mt], bb[nt], acc[mt][nt], 0, 0, 0);
    }
#pragma unroll
    for (int mt = 0; mt < 2; ++mt)
#pragma unroll
        for (int nt = 0; nt < 4; ++nt) {
            int rbase = m0 + mt * 16 + quad * 4;
            int col = nt * 16 + l16;
#pragma unroll
            for (int r = 0; r < 4; ++r)
                logits[(long)(rbase + r) * 64 + col] = acc[mt][nt][r];
        }
}

// ---------------- K4: +bd, softmax over 50 tags (one wave per row) ----------
__global__ __launch_bounds__(256) void k_softmax(const float* __restrict__ logits,
                                                 const float* __restrict__ bd,
                                                 float* __restrict__ out) {
    int w = threadIdx.x >> 6, lane = threadIdx.x & 63;
    long r = (long)blockIdx.x * 4 + w;
    float x = (lane < TAGS_) ? logits[r * 64 + lane] + bd[lane] : -3.0e38f;
    float m = x;
#pragma unroll
    for (int off = 32; off >= 1; off >>= 1) m = fmaxf(m, __shfl_xor(m, off, 64));
    float e = (lane < TAGS_) ? __expf(x - m) : 0.0f;
    float ssum = e;
#pragma unroll
    for (int off = 32; off >= 1; off >>= 1) ssum += __shfl_xor(ssum, off, 64);
    if (lane < TAGS_) out[r * TAGS_ + lane] = e / ssum;
}

extern "C" void kernel_launch(void* const* d_in, const int* in_sizes, int n_in,
                              void* d_out, int out_size, void* d_ws, size_t ws_size,
                              hipStream_t stream) {
    (void)in_sizes; (void)n_in; (void)out_size; (void)ws_size;
    const int*   tokens = (const int*)  d_in[0];
    const float* emb    = (const float*)d_in[1];
    const float* Wx_f   = (const float*)d_in[2];
    const float* Wh_f   = (const float*)d_in[3];
    const float* b_f    = (const float*)d_in[4];
    const float* Wx_b   = (const float*)d_in[5];
    const float* Wh_b   = (const float*)d_in[6];
    const float* b_b    = (const float*)d_in[7];
    const float* Wd     = (const float*)d_in[8];
    const float* bd     = (const float*)d_in[9];
    float* out = (float*)d_out;

    // workspace layout (bytes): total 190,119,936
    uint8_t* w = (uint8_t*)d_ws;
    unsigned short* X16    = (unsigned short*)(w);                  // 20,971,520 (dead after K1)
    // aliases inside X16's region, used only after K1:
    unsigned short* WhP    = (unsigned short*)(w);                  //  1,048,576
    unsigned char*  WhP8   = (unsigned char*)(w + 1048576);         //    393,216
    unsigned short* W16T   = (unsigned short*)(w + 20971520);       //  1,310,720
    unsigned short* WdT16  = (unsigned short*)(w + 22282240);       //     65,536
    unsigned long long* xzP = (unsigned long long*)(w + 22347776);  // 134,217,728
    unsigned short* hcat16 = (unsigned short*)(w + 156565504);      //  33,554,432
    float*          logits = (float*)(w + 22347776);                // alias xzP (dead after K2)

    k_gather_x  <<<dim3(NROWS),     dim3(KPAD), 0, stream>>>(tokens, emb, X16);
    k_prep_w    <<<dim3(NCOLS),     dim3(KPAD), 0, stream>>>(Wx_f, Wx_b, W16T);
    k_prep_wd   <<<dim3(64),        dim3(512),  0, stream>>>(Wd, WdT16);
    k_gemm_xz   <<<dim3(256, 16),   dim3(256),  0, stream>>>(X16, W16T, b_f, b_b, xzP);
    // X16 region now dead -> build WhP / WhP8 in it
    k_prep_wh   <<<dim3(2048),      dim3(256),  0, stream>>>(Wh_f, Wh_b, WhP);
    k_prep_wh8  <<<dim3(1536),      dim3(256),  0, stream>>>(Wh_f, Wh_b, WhP8);
    k_recurrence<<<dim3(256),       dim3(256),  0, stream>>>(WhP, WhP8, xzP, hcat16);
    k_gemm_logits<<<dim3(256),      dim3(256),  0, stream>>>(hcat16, WdT16, logits);
    k_softmax   <<<dim3(NROWS / 4), dim3(256),  0, stream>>>(logits, bd, out);
}

// Round 5
// 672.717 us; speedup vs baseline: 1.0269x; 1.0269x over previous
//
#include <hip/hip_runtime.h>
#include <stdint.h>

#define B_    128
#define S_    256
#define EMB_  300
#define HID_  256
#define TAGS_ 50
#define KPAD  320           // EMB padded to multiple of 32
#define NROWS (B_ * S_)     // 32768, row r = s*128 + b
#define GF    (4 * HID_)    // 1024 gate cols per direction
#define NCOLS (2 * GF)      // 2048 (fwd | bwd)

typedef __bf16 bf16x8 __attribute__((ext_vector_type(8)));
typedef float  f32x4  __attribute__((ext_vector_type(4)));
typedef unsigned int u32x4 __attribute__((ext_vector_type(4)));
typedef int    i32x8  __attribute__((ext_vector_type(8)));

__device__ __forceinline__ unsigned short f2bf(float f) {
    unsigned int u = __float_as_uint(f);
    unsigned int r = (u + 0x7fffu + ((u >> 16) & 1u)) >> 16;  // RNE
    return (unsigned short)r;
}
__device__ __forceinline__ bf16x8 ldb8(const unsigned short* p) {
    u32x4 v = *reinterpret_cast<const u32x4*>(p);
    return __builtin_bit_cast(bf16x8, v);
}
// fast sigmoid: v_exp_f32 + v_rcp_f32 (no IEEE div expansion; ~1ulp rcp err)
__device__ __forceinline__ float sigf(float x) {
    return __builtin_amdgcn_rcpf(1.0f + __builtin_amdgcn_exp2f(x * -1.44269504f));
}
// 4-way select by q (2-level cndmask chain, no dynamic indexing)
__device__ __forceinline__ float sel4(float v0, float v1, float v2, float v3, int q) {
    float a = (q & 1) ? v1 : v0;
    float b = (q & 1) ? v3 : v2;
    return (q & 2) ? b : a;
}

// ---------------- K0a: embedding gather -> bf16, K-padded -------------------
__global__ void k_gather_x(const int* __restrict__ tokens, const float* __restrict__ emb,
                           unsigned short* __restrict__ X16) {
    int r = blockIdx.x;            // r = s*128 + b
    int k = threadIdx.x;           // 0..319
    int b = r & 127, s = r >> 7;
    int tok = tokens[b * S_ + s];
    float v = (k < EMB_) ? emb[(long)tok * EMB_ + k] : 0.0f;
    X16[(long)r * KPAD + k] = f2bf(v);
}

// ---------------- K0b: Wx (f|b) -> transposed bf16 [2048][320] --------------
__global__ void k_prep_w(const float* __restrict__ Wx_f, const float* __restrict__ Wx_b,
                         unsigned short* __restrict__ W16T) {
    int c = blockIdx.x;            // 0..2047
    int k = threadIdx.x;           // 0..319
    float v = 0.0f;
    if (k < EMB_) v = (c < GF) ? Wx_f[k * GF + c] : Wx_b[k * GF + (c - GF)];
    W16T[c * KPAD + k] = f2bf(v);
}

// ---------------- K0c: Wd -> transposed bf16 [64][512] ----------------------
__global__ void k_prep_wd(const float* __restrict__ Wd, unsigned short* __restrict__ WdT16) {
    int c = blockIdx.x;            // 0..63
    int k = threadIdx.x;           // 0..511
    float v = (c < TAGS_) ? Wd[k * TAGS_ + c] : 0.0f;
    WdT16[c * 512 + k] = f2bf(v);
}

// ---------------- K0d: Wh -> packed bf16 [2 dir][4 sl][256 c][256 k] --------
__global__ void k_prep_wh(const float* __restrict__ Wh_f, const float* __restrict__ Wh_b,
                          unsigned short* __restrict__ WhP) {
    int row = blockIdx.x;          // 0..2047 = (d*4+sl)*256 + c
    int k = threadIdx.x;           // 0..255
    int d = row >> 10, sl = (row >> 8) & 3, c = row & 255;
    int gate = c >> 6, jrel = c & 63;
    const float* Wh = d ? Wh_b : Wh_f;
    WhP[(long)row * 256 + k] = f2bf(Wh[k * GF + gate * HID_ + sl * 64 + jrel]);
}

// ---------------- K0e: Wh gates i,f,o -> fp8 e4m3 [2 dir][3 g][256 j][256 k]-
__global__ void k_prep_wh8(const float* __restrict__ Wh_f, const float* __restrict__ Wh_b,
                           unsigned char* __restrict__ WhP8) {
    int row = blockIdx.x;          // 0..1535 = (d*3+gi)*256 + j
    int k = threadIdx.x;           // 0..255
    int d = row / 768, rr = row - d * 768, gi = rr >> 8, j = rr & 255;
    int ga = (gi == 2) ? 3 : gi;   // i=0, f=1, o=3
    const float* Wh = d ? Wh_b : Wh_f;
    float v = Wh[k * GF + ga * HID_ + j];
    int p = __builtin_amdgcn_cvt_pk_fp8_f32(v, 0.0f, 0, false);
    WhP8[(long)row * 256 + k] = (unsigned char)(p & 0xff);
}

// ---------------- K1: xz = X @ Wx + b  (MFMA, LDS-free) ---------------------
// xzP gate-major layout: u64 idx = ((s*16+g16)*64 + gate*16 + u16)*64 + b4*16 + j
// (u64 packs 4 batches b4*4+{0..3} as bf16). Producer stores are 512 B/wave
// contiguous; consumer reads are per-lane ushort picks (see K2).
__global__ __launch_bounds__(256) void k_gemm_xz(
    const unsigned short* __restrict__ X16, const unsigned short* __restrict__ W16T,
    const float* __restrict__ b_f, const float* __restrict__ b_b,
    unsigned long long* __restrict__ xzP) {
    int w = threadIdx.x >> 6, lane = threadIdx.x & 63;
    int quad = lane >> 4, l16 = lane & 15;
    int m0 = blockIdx.x * 128 + w * 32;
    int n0 = blockIdx.y * 128;
    f32x4 acc[2][8];
#pragma unroll
    for (int mt = 0; mt < 2; ++mt)
#pragma unroll
        for (int nt = 0; nt < 8; ++nt) acc[mt][nt] = (f32x4){0.f, 0.f, 0.f, 0.f};

    int koff = quad * 8;
#pragma unroll
    for (int ks = 0; ks < 10; ++ks) {
        int k0 = ks * 32 + koff;
        bf16x8 a[2], bb[8];
#pragma unroll
        for (int mt = 0; mt < 2; ++mt)
            a[mt] = ldb8(X16 + (long)(m0 + mt * 16 + l16) * KPAD + k0);
#pragma unroll
        for (int nt = 0; nt < 8; ++nt)
            bb[nt] = ldb8(W16T + (long)(n0 + nt * 16 + l16) * KPAD + k0);
#pragma unroll
        for (int mt = 0; mt < 2; ++mt)
#pragma unroll
            for (int nt = 0; nt < 8; ++nt)
                acc[mt][nt] = __builtin_amdgcn_mfma_f32_16x16x32_bf16(a[mt], bb[nt], acc[mt][nt], 0, 0, 0);
    }
    int s = blockIdx.x;            // m>>7
#pragma unroll
    for (int mt = 0; mt < 2; ++mt) {
        int grp = w * 2 + mt;      // (b>>4)
#pragma unroll
        for (int nt = 0; nt < 8; ++nt) {
            int col = n0 + nt * 16 + l16;
            int dir = col >> 10, cc = col & 1023;
            int gate = cc >> 8, u16 = (cc & 255) >> 4;
            float bias = dir ? b_b[cc] : b_f[cc];
            unsigned long long pk = 0;
#pragma unroll
            for (int r = 0; r < 4; ++r)
                pk |= (unsigned long long)f2bf(acc[mt][nt][r] + bias) << (16 * r);
            long idx8 = ((long)(s * 16 + dir * 8 + grp)) * 4096 +
                        (gate * 16 + u16) * 64 + quad * 16 + l16;
            xzP[idx8] = pk;
        }
    }
}

// ---------------- K2: bidirectional LSTM recurrence, single-CU chains -------
// Round-5: n_b=1 with 512 threads (256 blocks = 2 dir x 128 batches, XCD-
// grouped remap from r4 kept: FETCH stayed 68 MB). Lessons encoded:
//  - r3: step = MFMA-issue(1449/SIMD, invariant) + VALU(cells/SIMD-driven),
//    phases SUM (serial chain). 2 waves/SIMD lockstep => ~0 stall.
//  - r4: 1 wave/SIMD exposes ~1300 cyc latency => ALWAYS keep 2 waves/SIMD.
// New: gate VALU concentrated on ONE wave per SIMD (waves 0-3, 1 cell/lane).
// MFMA waves export z via LDS: quad q stores gate q (i,f,g,o) for its 2 cols
// (6 cndmask + 2 ds_write_b32, 2 lanes/bank = free); gate wave reads
// z[col][0..3] as one ds_read_b128 (contiguous, conflict-free). Costs ~100cyc
// z-routing + 1 extra barrier, saves ~425cyc of duplicated gate VALU.
// A-reads are uniform-address broadcasts (n_b=1) => 0 bank conflicts (r4).
__global__ __launch_bounds__(512, 2) void k_recurrence(
    const unsigned short* __restrict__ WhP, const unsigned char* __restrict__ WhP8,
    const unsigned long long* __restrict__ xzP, unsigned short* __restrict__ hcat16) {
    __shared__ __align__(16) unsigned char lds[5632];
    const int HB = 0, H8 = 1024, ZB = 1536;  // hb 2x512B | h8 2x256B | z 256x4 f32
    int tid = threadIdx.x;
    int w = tid >> 6, lane = tid & 63, quad = lane >> 4, l16 = lane & 15;
    // XCD-grouped bijective block->(d,b): x=blk&7 is the XCD; the 4 batches
    // of one b4-group (shared xzP cachelines) land on the same XCD.
    int blk = blockIdx.x;
    int x = blk & 7, t0 = blk >> 3;
    int j4 = t0 & 3, pslot = t0 >> 2;
    int pr = pslot * 8 + x;        // 0..63 = d*32 + g
    int d = pr >> 5, g = pr & 31;
    int b = 4 * g + j4;            // block's single batch

    // g-gate bf16 weight fragments, register-pinned (64 VGPR); wave w covers
    // cols 16*(2w+g2)+l16
    u32x4 whg[2][8];
#pragma unroll
    for (int g2 = 0; g2 < 2; ++g2) {
        int j = 16 * (2 * w + g2) + l16;
        int sl = j >> 6, jrel = j & 63;
        const unsigned short* src = WhP + ((long)((d * 4 + sl) * 256 + 128 + jrel)) * 256;
#pragma unroll
        for (int kt = 0; kt < 8; ++kt) {
            u32x4 v = *reinterpret_cast<const u32x4*>(src + kt * 32 + quad * 8);
            asm volatile("" : "+v"(v));
            whg[g2][kt] = v;
        }
    }
    // i/f/o fp8 K=128 scaled-MFMA B fragments, register-pinned (96 VGPR)
    i32x8 wh8s[3][2][2];
#pragma unroll
    for (int gi = 0; gi < 3; ++gi)
#pragma unroll
        for (int g2 = 0; g2 < 2; ++g2)
#pragma unroll
            for (int kt2 = 0; kt2 < 2; ++kt2) {
                const unsigned char* wp8 = WhP8 +
                    ((long)((d * 3 + gi) * 256 + 16 * (2 * w + g2) + l16)) * 256 +
                    kt2 * 128 + quad * 32;
                i32x8 v = *reinterpret_cast<const i32x8*>(wp8);
                asm volatile("" : "+v"(v));
                wh8s[gi][g2][kt2] = v;
            }

    float c2 = 0.f;
    // gate-wave state (tid<256): lane owns col=tid of batch b
    int col = tid;                              // valid when tid<256
    int g16 = d * 8 + (b >> 4);
    const unsigned short* xzU = (const unsigned short*)xzP;
    unsigned int laneoff = (unsigned)((col >> 4) * 256 + ((b >> 2) & 3) * 64 +
                                      (col & 15) * 4 + (b & 3));
    unsigned short xzu[4] = {0, 0, 0, 0};
    if (tid < 256) {
        int s0 = d ? 255 : 0;
        const unsigned short* ps = xzU + (unsigned long)(s0 * 16 + g16) * 16384;
#pragma unroll
        for (int ga = 0; ga < 4; ++ga) xzu[ga] = ps[laneoff + ga * 4096];
    }

    for (int t = 0; t < 256; ++t) {
        int s = d ? (255 - t) : t;
        int pb = t & 1, cb = pb ^ 1;
        f32x4 accg[2];
        f32x4 acc8[3][2];
#pragma unroll
        for (int g2 = 0; g2 < 2; ++g2) {
            accg[g2] = (f32x4){0.f, 0.f, 0.f, 0.f};
#pragma unroll
            for (int gi = 0; gi < 3; ++gi) acc8[gi][g2] = (f32x4){0.f, 0.f, 0.f, 0.f};
        }

        if (t > 0) {
#pragma unroll
            for (int kt = 0; kt < 8; ++kt) {
                // single batch -> same-address 16-lane broadcast (0 conflicts)
                bf16x8 A = ldb8(reinterpret_cast<const unsigned short*>(
                    lds + HB + cb * 512 + kt * 64 + quad * 16));
#pragma unroll
                for (int g2 = 0; g2 < 2; ++g2)
                    accg[g2] = __builtin_amdgcn_mfma_f32_16x16x32_bf16(
                        A, __builtin_bit_cast(bf16x8, whg[g2][kt]), accg[g2], 0, 0, 0);
            }
#pragma unroll
            for (int kt2 = 0; kt2 < 2; ++kt2) {
                i32x8 A8 = *reinterpret_cast<const i32x8*>(
                    lds + H8 + cb * 256 + kt2 * 128 + quad * 32);
#pragma unroll
                for (int g2 = 0; g2 < 2; ++g2)
#pragma unroll
                    for (int gi = 0; gi < 3; ++gi)
#if __has_builtin(__builtin_amdgcn_mfma_scale_f32_16x16x128_f8f6f4)
                        acc8[gi][g2] = __builtin_amdgcn_mfma_scale_f32_16x16x128_f8f6f4(
                            A8, wh8s[gi][g2][kt2], acc8[gi][g2], 0, 0, 0, 0x7F, 0, 0x7F);
#else
                        acc8[gi][g2] = acc8[gi][g2];  // unreachable on gfx950
#endif
            }
        }
        // z export: quad q stores gate q (i,f,g,o) for its 2 cols. All C rows
        // equal (single batch) -> element 0. Layout z[col][gate] f32: word
        // addr mod 32 = 4*l16+quad -> exactly 2 lanes/bank (free).
#pragma unroll
        for (int g2 = 0; g2 < 2; ++g2) {
            int cw = 16 * (2 * w + g2) + l16;
            float zv = sel4(acc8[0][g2][0], acc8[1][g2][0], accg[g2][0], acc8[2][g2][0], quad);
            *reinterpret_cast<float*>(lds + ZB + (cw * 4 + quad) * 4) = zv;
        }
        // barrier 1: z visible. LDS-only wait (no vmcnt drain).
        asm volatile("s_waitcnt lgkmcnt(0)\n\ts_barrier" ::: "memory");

        if (tid < 256) {   // gate waves: 1 per SIMD, 1 cell per lane
            float xa0 = __uint_as_float((unsigned int)xzu[0] << 16);
            float xa1 = __uint_as_float((unsigned int)xzu[1] << 16);
            float xa2 = __uint_as_float((unsigned int)xzu[2] << 16);
            float xa3 = __uint_as_float((unsigned int)xzu[3] << 16);
            // prefetch next step (full step of slack before consumption)
            {
                int sn = d ? (s ? s - 1 : 0) : (s < 255 ? s + 1 : 255);
                const unsigned short* ps = xzU + (unsigned long)(sn * 16 + g16) * 16384;
#pragma unroll
                for (int ga = 0; ga < 4; ++ga) xzu[ga] = ps[laneoff + ga * 4096];
            }
            f32x4 z4 = *reinterpret_cast<const f32x4*>(lds + ZB + col * 16);
            float zi = z4[0] + xa0;
            float zf = z4[1] + xa1;
            float zg = z4[2] + xa2;
            float zo = z4[3] + xa3;
            float c = sigf(zf) * c2 + sigf(zi) * fmaxf(zg, 0.0f);
            c2 = c;
            float h = sigf(zo) * fmaxf(c, 0.0f);

            unsigned short hb16 = f2bf(h);
            *reinterpret_cast<unsigned short*>(lds + HB + pb * 512 + col * 2) = hb16;
            int p8 = __builtin_amdgcn_cvt_pk_fp8_f32(h, h, 0, false);
            *(lds + H8 + pb * 256 + col) = (unsigned char)(p8 & 0xff);
            // hcat direct from register (fire-and-forget; barrier won't drain)
            hcat16[((long)b * S_ + s) * 512 + d * HID_ + col] = hb16;
        }
        // barrier 2: h ready for next step's A-reads. LDS-only wait.
        asm volatile("s_waitcnt lgkmcnt(0)\n\ts_barrier" ::: "memory");
    }
}

// ---------------- K3: logits = hcat @ Wd  (MFMA, N padded to 64) ------------
__global__ __launch_bounds__(256) void k_gemm_logits(
    const unsigned short* __restrict__ hcat16, const unsigned short* __restrict__ WdT16,
    float* __restrict__ logits) {
    int w = threadIdx.x >> 6, lane = threadIdx.x & 63;
    int quad = lane >> 4, l16 = lane & 15;
    int m0 = blockIdx.x * 128 + w * 32;
    f32x4 acc[2][4];
#pragma unroll
    for (int mt = 0; mt < 2; ++mt)
#pragma unroll
        for (int nt = 0; nt < 4; ++nt) acc[mt][nt] = (f32x4){0.f, 0.f, 0.f, 0.f};
#pragma unroll
    for (int ks = 0; ks < 16; ++ks) {
        int k0 = ks * 32 + quad * 8;
        bf16x8 a[2], bb[4];
#pragma unroll
        for (int mt = 0; mt < 2; ++mt)
            a[mt] = ldb8(hcat16 + (long)(m0 + mt * 16 + l16) * 512 + k0);
#pragma unroll
        for (int nt = 0; nt < 4; ++nt)
            bb[nt] = ldb8(WdT16 + (long)(nt * 16 + l16) * 512 + k0);
#pragma unroll
        for (int mt = 0; mt < 2; ++mt)
#pragma unroll
            for (int nt = 0; nt < 4; ++nt)
                acc[mt][nt] = __builtin_amdgcn_mfma_f32_16x16x32_bf16(a[mt], bb[nt], acc[mt][nt], 0, 0, 0);
    }
#pragma unroll
    for (int mt = 0; mt < 2; ++mt)
#pragma unroll
        for (int nt = 0; nt < 4; ++nt) {
            int rbase = m0 + mt * 16 + quad * 4;
            int col = nt * 16 + l16;
#pragma unroll
            for (int r = 0; r < 4; ++r)
                logits[(long)(rbase + r) * 64 + col] = acc[mt][nt][r];
        }
}

// ---------------- K4: +bd, softmax over 50 tags (one wave per row) ----------
__global__ __launch_bounds__(256) void k_softmax(const float* __restrict__ logits,
                                                 const float* __restrict__ bd,
                                                 float* __restrict__ out) {
    int w = threadIdx.x >> 6, lane = threadIdx.x & 63;
    long r = (long)blockIdx.x * 4 + w;
    float x = (lane < TAGS_) ? logits[r * 64 + lane] + bd[lane] : -3.0e38f;
    float m = x;
#pragma unroll
    for (int off = 32; off >= 1; off >>= 1) m = fmaxf(m, __shfl_xor(m, off, 64));
    float e = (lane < TAGS_) ? __expf(x - m) : 0.0f;
    float ssum = e;
#pragma unroll
    for (int off = 32; off >= 1; off >>= 1) ssum += __shfl_xor(ssum, off, 64);
    if (lane < TAGS_) out[r * TAGS_ + lane] = e / ssum;
}

extern "C" void kernel_launch(void* const* d_in, const int* in_sizes, int n_in,
                              void* d_out, int out_size, void* d_ws, size_t ws_size,
                              hipStream_t stream) {
    (void)in_sizes; (void)n_in; (void)out_size; (void)ws_size;
    const int*   tokens = (const int*)  d_in[0];
    const float* emb    = (const float*)d_in[1];
    const float* Wx_f   = (const float*)d_in[2];
    const float* Wh_f   = (const float*)d_in[3];
    const float* b_f    = (const float*)d_in[4];
    const float* Wx_b   = (const float*)d_in[5];
    const float* Wh_b   = (const float*)d_in[6];
    const float* b_b    = (const float*)d_in[7];
    const float* Wd     = (const float*)d_in[8];
    const float* bd     = (const float*)d_in[9];
    float* out = (float*)d_out;

    // workspace layout (bytes): total 190,119,936
    uint8_t* w = (uint8_t*)d_ws;
    unsigned short* X16    = (unsigned short*)(w);                  // 20,971,520 (dead after K1)
    // aliases inside X16's region, used only after K1:
    unsigned short* WhP    = (unsigned short*)(w);                  //  1,048,576
    unsigned char*  WhP8   = (unsigned char*)(w + 1048576);         //    393,216
    unsigned short* W16T   = (unsigned short*)(w + 20971520);       //  1,310,720
    unsigned short* WdT16  = (unsigned short*)(w + 22282240);       //     65,536
    unsigned long long* xzP = (unsigned long long*)(w + 22347776);  // 134,217,728
    unsigned short* hcat16 = (unsigned short*)(w + 156565504);      //  33,554,432
    float*          logits = (float*)(w + 22347776);                // alias xzP (dead after K2)

    k_gather_x  <<<dim3(NROWS),     dim3(KPAD), 0, stream>>>(tokens, emb, X16);
    k_prep_w    <<<dim3(NCOLS),     dim3(KPAD), 0, stream>>>(Wx_f, Wx_b, W16T);
    k_prep_wd   <<<dim3(64),        dim3(512),  0, stream>>>(Wd, WdT16);
    k_gemm_xz   <<<dim3(256, 16),   dim3(256),  0, stream>>>(X16, W16T, b_f, b_b, xzP);
    // X16 region now dead -> build WhP / WhP8 in it
    k_prep_wh   <<<dim3(2048),      dim3(256),  0, stream>>>(Wh_f, Wh_b, WhP);
    k_prep_wh8  <<<dim3(1536),      dim3(256),  0, stream>>>(Wh_f, Wh_b, WhP8);
    k_recurrence<<<dim3(256),       dim3(512),  0, stream>>>(WhP, WhP8, xzP, hcat16);
    k_gemm_logits<<<dim3(256),      dim3(256),  0, stream>>>(hcat16, WdT16, logits);
    k_softmax   <<<dim3(NROWS / 4), dim3(256),  0, stream>>>(logits, bd, out);
}

// Round 6
// 456.305 us; speedup vs baseline: 1.5140x; 1.4743x over previous
//
#include <hip/hip_runtime.h>
#include <stdint.h>

#define B_    128
#define S_    256
#define EMB_  300
#define HID_  256
#define TAGS_ 50
#define KPAD  320           // EMB padded to multiple of 32
#define NROWS (B_ * S_)     // 32768, row r = s*128 + b
#define GF    (4 * HID_)    // 1024 gate cols per direction
#define NCOLS (2 * GF)      // 2048 (fwd | bwd)

typedef __bf16 bf16x8 __attribute__((ext_vector_type(8)));
typedef float  f32x4  __attribute__((ext_vector_type(4)));
typedef unsigned int u32x4 __attribute__((ext_vector_type(4)));
typedef int    i32x8  __attribute__((ext_vector_type(8)));

__device__ __forceinline__ unsigned short f2bf(float f) {
    unsigned int u = __float_as_uint(f);
    unsigned int r = (u + 0x7fffu + ((u >> 16) & 1u)) >> 16;  // RNE
    return (unsigned short)r;
}
__device__ __forceinline__ bf16x8 ldb8(const unsigned short* p) {
    u32x4 v = *reinterpret_cast<const u32x4*>(p);
    return __builtin_bit_cast(bf16x8, v);
}
// fast sigmoid: v_exp_f32 + v_rcp_f32 (no IEEE div expansion; ~1ulp rcp err)
__device__ __forceinline__ float sigf(float x) {
    return __builtin_amdgcn_rcpf(1.0f + __builtin_amdgcn_exp2f(x * -1.44269504f));
}
// element (p) of an f32x4 pair-slot without dynamic vector indexing
__device__ __forceinline__ float sel2(f32x4 v, int p) {
    return p ? v[1] : v[0];   // rows {p, p+2} hold identical values; take p
}
// async global->LDS, 16B per lane (dest = wave-uniform base + lane*16)
__device__ __forceinline__ void gload_lds16(const void* g, void* l) {
    __builtin_amdgcn_global_load_lds(
        (const __attribute__((address_space(1))) void*)g,
        (__attribute__((address_space(3))) void*)l, 16, 0, 0);
}

// ---------------- K0a: embedding gather -> bf16, K-padded -------------------
__global__ void k_gather_x(const int* __restrict__ tokens, const float* __restrict__ emb,
                           unsigned short* __restrict__ X16) {
    int r = blockIdx.x;            // r = s*128 + b
    int k = threadIdx.x;           // 0..319
    int b = r & 127, s = r >> 7;
    int tok = tokens[b * S_ + s];
    float v = (k < EMB_) ? emb[(long)tok * EMB_ + k] : 0.0f;
    X16[(long)r * KPAD + k] = f2bf(v);
}

// ---------------- K0b: Wx (f|b) -> transposed bf16 [2048][320] --------------
__global__ void k_prep_w(const float* __restrict__ Wx_f, const float* __restrict__ Wx_b,
                         unsigned short* __restrict__ W16T) {
    int c = blockIdx.x;            // 0..2047
    int k = threadIdx.x;           // 0..319
    float v = 0.0f;
    if (k < EMB_) v = (c < GF) ? Wx_f[k * GF + c] : Wx_b[k * GF + (c - GF)];
    W16T[c * KPAD + k] = f2bf(v);
}

// ---------------- K0c: Wd -> transposed bf16 [64][512] ----------------------
__global__ void k_prep_wd(const float* __restrict__ Wd, unsigned short* __restrict__ WdT16) {
    int c = blockIdx.x;            // 0..63
    int k = threadIdx.x;           // 0..511
    float v = (c < TAGS_) ? Wd[k * TAGS_ + c] : 0.0f;
    WdT16[c * 512 + k] = f2bf(v);
}

// ---------------- K0d: Wh -> packed bf16 [2 dir][4 sl][256 c][256 k] --------
__global__ void k_prep_wh(const float* __restrict__ Wh_f, const float* __restrict__ Wh_b,
                          unsigned short* __restrict__ WhP) {
    int row = blockIdx.x;          // 0..2047 = (d*4+sl)*256 + c
    int k = threadIdx.x;           // 0..255
    int d = row >> 10, sl = (row >> 8) & 3, c = row & 255;
    int gate = c >> 6, jrel = c & 63;
    const float* Wh = d ? Wh_b : Wh_f;
    WhP[(long)row * 256 + k] = f2bf(Wh[k * GF + gate * HID_ + sl * 64 + jrel]);
}

// ---------------- K0e: Wh gates i,f,o -> fp8 e4m3 [2 dir][3 g][256 j][256 k]-
__global__ void k_prep_wh8(const float* __restrict__ Wh_f, const float* __restrict__ Wh_b,
                           unsigned char* __restrict__ WhP8) {
    int row = blockIdx.x;          // 0..1535 = (d*3+gi)*256 + j
    int k = threadIdx.x;           // 0..255
    int d = row / 768, rr = row - d * 768, gi = rr >> 8, j = rr & 255;
    int ga = (gi == 2) ? 3 : gi;   // i=0, f=1, o=3
    const float* Wh = d ? Wh_b : Wh_f;
    float v = Wh[k * GF + ga * HID_ + j];
    int p = __builtin_amdgcn_cvt_pk_fp8_f32(v, 0.0f, 0, false);
    WhP8[(long)row * 256 + k] = (unsigned char)(p & 0xff);
}

// ---------------- K1: xz = X @ Wx + b  (MFMA, LDS-staged, m97 pattern) ------
// Round-6 rewrite: the old K1 loaded every fragment straight from global
// (16 x 64B scattered transactions per ldb8, latency-bound, est. 150-200us).
// Now: 128x128 tile, BK=64, double-buffered LDS (64KB -> 2 blocks/CU),
// global_load_lds width=16 staging. T2 XOR-swizzle j^(row&7) applied on the
// GLOBAL SOURCE (gload_lds dest is linear: base+lane*16 — guide rule #21);
// ds_read side applies the same XOR -> 2 lanes/bank (free). Epilogue and acc
// mapping are byte-identical to the verified xzP packing.
__global__ __launch_bounds__(256) void k_gemm_xz(
    const unsigned short* __restrict__ X16, const unsigned short* __restrict__ W16T,
    const float* __restrict__ b_f, const float* __restrict__ b_b,
    unsigned long long* __restrict__ xzP) {
    __shared__ __align__(16) unsigned short Asw[2][128 * 64];  // 2 x 16 KB
    __shared__ __align__(16) unsigned short Bsw[2][128 * 64];  // 2 x 16 KB
    int w = threadIdx.x >> 6, lane = threadIdx.x & 63;
    int quad = lane >> 4, l16 = lane & 15;
    int m0 = blockIdx.x * 128;
    int n0 = blockIdx.y * 128;

    // staging geometry: instr i of wave w covers tile rows rb..rb+7 (128B/row)
    int rlane = lane >> 3;                 // 0..7 row within 8-row group
    int jpos  = lane & 7;                  // 16B-chunk position in LDS row
    // source chunk so that LDS[(r, jpos)] holds source chunk jpos^(r&7)
    // (r&7 == rlane&7 since row-group bases are multiples of 8)
    int jsrc  = jpos ^ (rlane & 7);

    f32x4 acc[2][8];
#pragma unroll
    for (int mt = 0; mt < 2; ++mt)
#pragma unroll
        for (int nt = 0; nt < 8; ++nt) acc[mt][nt] = (f32x4){0.f, 0.f, 0.f, 0.f};

#define STAGE(ST, BUFI) do {                                                    \
    int k0_ = (ST) * 64;                                                        \
    _Pragma("unroll")                                                           \
    for (int i_ = 0; i_ < 4; ++i_) {                                            \
        int rb_ = (w * 4 + i_) * 8;                                             \
        int r_  = rb_ + rlane;                                                  \
        gload_lds16(X16 + (long)(m0 + r_) * KPAD + k0_ + jsrc * 8,              \
                    &Asw[BUFI][rb_ * 64]);                                      \
    }                                                                           \
    _Pragma("unroll")                                                           \
    for (int i_ = 0; i_ < 4; ++i_) {                                            \
        int rb_ = (w * 4 + i_) * 8;                                             \
        int r_  = rb_ + rlane;                                                  \
        gload_lds16(W16T + (long)(n0 + r_) * KPAD + k0_ + jsrc * 8,             \
                    &Bsw[BUFI][rb_ * 64]);                                      \
    }                                                                           \
} while (0)

    STAGE(0, 0);
    __syncthreads();
#pragma unroll
    for (int st = 0; st < 5; ++st) {       // 5 x BK=64 = KPAD 320
        if (st < 4) STAGE(st + 1, (st + 1) & 1);
        int bufi = st & 1;
#pragma unroll
        for (int ks = 0; ks < 2; ++ks) {
            bf16x8 a[2], bb[8];
#pragma unroll
            for (int mt = 0; mt < 2; ++mt) {
                int mrow = w * 32 + mt * 16 + l16;
                int jp = (ks * 4 + quad) ^ (l16 & 7);
                a[mt] = ldb8(&Asw[bufi][mrow * 64 + jp * 8]);
            }
#pragma unroll
            for (int nt = 0; nt < 8; ++nt) {
                int nrow = nt * 16 + l16;
                int jp = (ks * 4 + quad) ^ (l16 & 7);
                bb[nt] = ldb8(&Bsw[bufi][nrow * 64 + jp * 8]);
            }
#pragma unroll
            for (int mt = 0; mt < 2; ++mt)
#pragma unroll
                for (int nt = 0; nt < 8; ++nt)
                    acc[mt][nt] = __builtin_amdgcn_mfma_f32_16x16x32_bf16(a[mt], bb[nt], acc[mt][nt], 0, 0, 0);
        }
        __syncthreads();
    }
#undef STAGE

    int s = blockIdx.x;            // m>>7
#pragma unroll
    for (int mt = 0; mt < 2; ++mt) {
        int grp = w * 2 + mt;      // (b>>4)
#pragma unroll
        for (int nt = 0; nt < 8; ++nt) {
            int col = n0 + nt * 16 + l16;
            int dir = col >> 10, cc = col & 1023;
            int gate = cc >> 8, u16 = (cc & 255) >> 4;
            float bias = dir ? b_b[cc] : b_f[cc];
            unsigned long long pk = 0;
#pragma unroll
            for (int r = 0; r < 4; ++r)
                pk |= (unsigned long long)f2bf(acc[mt][nt][r] + bias) << (16 * r);
            long idx8 = ((long)(s * 16 + dir * 8 + grp)) * 4096 +
                        (gate * 16 + u16) * 64 + quad * 16 + l16;
            xzP[idx8] = pk;
        }
    }
}

// ---------------- K2: bidirectional LSTM recurrence, single-CU chains -------
// r3 structure (the verified 245us optimum; r4/r5 variants regressed):
// 128 blocks = 2 dir x 64 batch-PAIRS, 512 threads, 2 lockstep waves/SIMD.
// step = MFMA-issue (~1449 cyc/SIMD, invariant) + VALU (~425 x n_b), phases
// sum through the serial chain; n_b=2 with 2 waves/SIMD is the local optimum
// (n_b=1 exposes latency (r4) or adds routing serialization (r5)).
__global__ __launch_bounds__(512, 2) void k_recurrence(
    const unsigned short* __restrict__ WhP, const unsigned char* __restrict__ WhP8,
    const unsigned long long* __restrict__ xzP, unsigned short* __restrict__ hcat16) {
    __shared__ __align__(16) unsigned char lds[3328];
    const int HB = 0, H8 = 2176;   // hb: 2 x 2 x 544 B; h8: 2 x 2 x 288 B
    int tid = threadIdx.x;
    int w = tid >> 6, lane = tid & 63, quad = lane >> 4, l16 = lane & 15;
    int blk = blockIdx.x;
    int d = blk >> 6, bg2 = blk & 63;           // batch pair b0 = bg2*2
    int p = quad & 1;                            // lane's batch parity
    int cg = quad >> 1;                          // lane's colgroup (0/1)
    int col = 16 * (2 * w + cg) + l16;           // lane's cell column
    int rp = l16 & 1;                            // A-row parity of this lane's row

    // g-gate bf16 weight fragments, register-pinned (64 VGPR) — both colgroups
    u32x4 whg[2][8];
#pragma unroll
    for (int cgi = 0; cgi < 2; ++cgi) {
        int j = 16 * (2 * w + cgi) + l16;
        int sl = j >> 6, jrel = j & 63;
        const unsigned short* src = WhP + ((long)((d * 4 + sl) * 256 + 128 + jrel)) * 256;
#pragma unroll
        for (int kt = 0; kt < 8; ++kt) {
            u32x4 v = *reinterpret_cast<const u32x4*>(src + kt * 32 + quad * 8);
            asm volatile("" : "+v"(v));
            whg[cgi][kt] = v;
        }
    }
    // i/f/o fp8 K=128 scaled-MFMA B fragments, register-pinned (96 VGPR)
    i32x8 wh8s[3][2][2];
#pragma unroll
    for (int gi = 0; gi < 3; ++gi)
#pragma unroll
        for (int cgi = 0; cgi < 2; ++cgi)
#pragma unroll
            for (int kt2 = 0; kt2 < 2; ++kt2) {
                const unsigned char* wp8 = WhP8 +
                    ((long)((d * 3 + gi) * 256 + 16 * (2 * w + cgi) + l16)) * 256 +
                    kt2 * 128 + quad * 32;
                i32x8 v = *reinterpret_cast<const i32x8*>(wp8);
                asm volatile("" : "+v"(v));
                wh8s[gi][cgi][kt2] = v;
            }

    float c2 = 0.f;

    // xz addressing: u16 index = (s*16 + rowc)*16384 + ga*4096 + laneoff
    const unsigned short* xzU = (const unsigned short*)xzP;
    int rowc = d * 8 + (bg2 >> 3);
    unsigned int laneoff = (unsigned)((2 * w + cg) * 256 +
                                      (((bg2 >> 1) & 3) * 16 + l16) * 4 +
                                      2 * (bg2 & 1) + p);

    // preload xz for first step (4 ushorts per lane: gates i,f,g,o)
    unsigned short xzu[4];
    {
        int s0 = d ? 255 : 0;
        const unsigned short* ps = xzU + (unsigned long)(s0 * 16 + rowc) * 16384;
#pragma unroll
        for (int ga = 0; ga < 4; ++ga) xzu[ga] = ps[laneoff + ga * 4096];
    }

    for (int t = 0; t < 256; ++t) {
        int s = d ? (255 - t) : t;
        int pb = t & 1, cb = pb ^ 1;
        f32x4 accg[2];
        f32x4 acc8[3][2];
#pragma unroll
        for (int cgi = 0; cgi < 2; ++cgi) {
            accg[cgi] = (f32x4){0.f, 0.f, 0.f, 0.f};
#pragma unroll
            for (int gi = 0; gi < 3; ++gi) acc8[gi][cgi] = (f32x4){0.f, 0.f, 0.f, 0.f};
        }

        if (t > 0) {
#pragma unroll
            for (int kt = 0; kt < 8; ++kt) {
                // A row l16 -> batch l16&1 (rows r and r+2 identical)
                bf16x8 A = ldb8(reinterpret_cast<const unsigned short*>(
                    lds + HB + cb * 1088 + rp * 544 + kt * 64 + quad * 16));
#pragma unroll
                for (int cgi = 0; cgi < 2; ++cgi)
                    accg[cgi] = __builtin_amdgcn_mfma_f32_16x16x32_bf16(
                        A, __builtin_bit_cast(bf16x8, whg[cgi][kt]), accg[cgi], 0, 0, 0);
            }
#pragma unroll
            for (int kt2 = 0; kt2 < 2; ++kt2) {
                i32x8 A8 = *reinterpret_cast<const i32x8*>(
                    lds + H8 + cb * 576 + rp * 288 + kt2 * 128 + quad * 32);
#pragma unroll
                for (int cgi = 0; cgi < 2; ++cgi)
#pragma unroll
                    for (int gi = 0; gi < 3; ++gi)
#if __has_builtin(__builtin_amdgcn_mfma_scale_f32_16x16x128_f8f6f4)
                        acc8[gi][cgi] = __builtin_amdgcn_mfma_scale_f32_16x16x128_f8f6f4(
                            A8, wh8s[gi][cgi][kt2], acc8[gi][cgi], 0, 0, 0, 0x7F, 0, 0x7F);
#else
                        acc8[gi][cgi] = acc8[gi][cgi];  // unreachable on gfx950
#endif
            }
        }
        // extract current-step xz addends (bf16 -> f32 is one shl each)
        float xa0 = __uint_as_float((unsigned int)xzu[0] << 16);
        float xa1 = __uint_as_float((unsigned int)xzu[1] << 16);
        float xa2 = __uint_as_float((unsigned int)xzu[2] << 16);
        float xa3 = __uint_as_float((unsigned int)xzu[3] << 16);
        // prefetch next step (fire-and-forget; consumed after next barrier)
        {
            int sn = d ? (s ? s - 1 : 0) : (s < 255 ? s + 1 : 255);
            const unsigned short* ps = xzU + (unsigned long)(sn * 16 + rowc) * 16384;
#pragma unroll
            for (int ga = 0; ga < 4; ++ga) xzu[ga] = ps[laneoff + ga * 4096];
        }
        // gates: lane's cell (batch bg2*2+p, col). C row m=quad*4+r has batch
        // m&1=r&1 -> element p (== element p+2). Colgroup pick by cg.
        float zi = (cg ? sel2(acc8[0][1], p) : sel2(acc8[0][0], p)) + xa0;
        float zf = (cg ? sel2(acc8[1][1], p) : sel2(acc8[1][0], p)) + xa1;
        float zg = (cg ? sel2(accg[1],    p) : sel2(accg[0],    p)) + xa2;
        float zo = (cg ? sel2(acc8[2][1], p) : sel2(acc8[2][0], p)) + xa3;
        float c = sigf(zf) * c2 + sigf(zi) * fmaxf(zg, 0.0f);
        c2 = c;
        float h = sigf(zo) * fmaxf(c, 0.0f);

        unsigned short hb16 = f2bf(h);
        *reinterpret_cast<unsigned short*>(lds + HB + pb * 1088 + p * 544 + col * 2) = hb16;
        int p8 = __builtin_amdgcn_cvt_pk_fp8_f32(h, h, 0, false);
        *(lds + H8 + pb * 576 + p * 288 + col) = (unsigned char)(p8 & 0xff);
        // hcat direct from register (fire-and-forget; barrier won't drain it)
        hcat16[((long)(bg2 * 2 + p) * S_ + s) * 512 + d * HID_ + col] = hb16;
        // LDS-only barrier: no vmcnt drain (global stores/loads stay in flight)
        asm volatile("s_waitcnt lgkmcnt(0)\n\ts_barrier" ::: "memory");
    }
}

// ---------------- K3: logits = hcat @ Wd  (MFMA, N padded to 64) ------------
__global__ __launch_bounds__(256) void k_gemm_logits(
    const unsigned short* __restrict__ hcat16, const unsigned short* __restrict__ WdT16,
    float* __restrict__ logits) {
    int w = threadIdx.x >> 6, lane = threadIdx.x & 63;
    int quad = lane >> 4, l16 = lane & 15;
    int m0 = blockIdx.x * 128 + w * 32;
    f32x4 acc[2][4];
#pragma unroll
    for (int mt = 0; mt < 2; ++mt)
#pragma unroll
        for (int nt = 0; nt < 4; ++nt) acc[mt][nt] = (f32x4){0.f, 0.f, 0.f, 0.f};
#pragma unroll
    for (int ks = 0; ks < 16; ++ks) {
        int k0 = ks * 32 + quad * 8;
        bf16x8 a[2], bb[4];
#pragma unroll
        for (int mt = 0; mt < 2; ++mt)
            a[mt] = ldb8(hcat16 + (long)(m0 + mt * 16 + l16) * 512 + k0);
#pragma unroll
        for (int nt = 0; nt < 4; ++nt)
            bb[nt] = ldb8(WdT16 + (long)(nt * 16 + l16) * 512 + k0);
#pragma unroll
        for (int mt = 0; mt < 2; ++mt)
#pragma unroll
            for (int nt = 0; nt < 4; ++nt)
                acc[mt][nt] = __builtin_amdgcn_mfma_f32_16x16x32_bf16(a[mt], bb[nt], acc[mt][nt], 0, 0, 0);
    }
#pragma unroll
    for (int mt = 0; mt < 2; ++mt)
#pragma unroll
        for (int nt = 0; nt < 4; ++nt) {
            int rbase = m0 + mt * 16 + quad * 4;
            int col = nt * 16 + l16;
#pragma unroll
            for (int r = 0; r < 4; ++r)
                logits[(long)(rbase + r) * 64 + col] = acc[mt][nt][r];
        }
}

// ---------------- K4: +bd, softmax over 50 tags (one wave per row) ----------
__global__ __launch_bounds__(256) void k_softmax(const float* __restrict__ logits,
                                                 const float* __restrict__ bd,
                                                 float* __restrict__ out) {
    int w = threadIdx.x >> 6, lane = threadIdx.x & 63;
    long r = (long)blockIdx.x * 4 + w;
    float x = (lane < TAGS_) ? logits[r * 64 + lane] + bd[lane] : -3.0e38f;
    float m = x;
#pragma unroll
    for (int off = 32; off >= 1; off >>= 1) m = fmaxf(m, __shfl_xor(m, off, 64));
    float e = (lane < TAGS_) ? __expf(x - m) : 0.0f;
    float ssum = e;
#pragma unroll
    for (int off = 32; off >= 1; off >>= 1) ssum += __shfl_xor(ssum, off, 64);
    if (lane < TAGS_) out[r * TAGS_ + lane] = e / ssum;
}

extern "C" void kernel_launch(void* const* d_in, const int* in_sizes, int n_in,
                              void* d_out, int out_size, void* d_ws, size_t ws_size,
                              hipStream_t stream) {
    (void)in_sizes; (void)n_in; (void)out_size; (void)ws_size;
    const int*   tokens = (const int*)  d_in[0];
    const float* emb    = (const float*)d_in[1];
    const float* Wx_f   = (const float*)d_in[2];
    const float* Wh_f   = (const float*)d_in[3];
    const float* b_f    = (const float*)d_in[4];
    const float* Wx_b   = (const float*)d_in[5];
    const float* Wh_b   = (const float*)d_in[6];
    const float* b_b    = (const float*)d_in[7];
    const float* Wd     = (const float*)d_in[8];
    const float* bd     = (const float*)d_in[9];
    float* out = (float*)d_out;

    // workspace layout (bytes): total 190,119,936
    uint8_t* w = (uint8_t*)d_ws;
    unsigned short* X16    = (unsigned short*)(w);                  // 20,971,520 (dead after K1)
    // aliases inside X16's region, used only after K1:
    unsigned short* WhP    = (unsigned short*)(w);                  //  1,048,576
    unsigned char*  WhP8   = (unsigned char*)(w + 1048576);         //    393,216
    unsigned short* W16T   = (unsigned short*)(w + 20971520);       //  1,310,720
    unsigned short* WdT16  = (unsigned short*)(w + 22282240);       //     65,536
    unsigned long long* xzP = (unsigned long long*)(w + 22347776);  // 134,217,728
    unsigned short* hcat16 = (unsigned short*)(w + 156565504);      //  33,554,432
    float*          logits = (float*)(w + 22347776);                // alias xzP (dead after K2)

    k_gather_x  <<<dim3(NROWS),     dim3(KPAD), 0, stream>>>(tokens, emb, X16);
    k_prep_w    <<<dim3(NCOLS),     dim3(KPAD), 0, stream>>>(Wx_f, Wx_b, W16T);
    k_prep_wd   <<<dim3(64),        dim3(512),  0, stream>>>(Wd, WdT16);
    k_gemm_xz   <<<dim3(256, 16),   dim3(256),  0, stream>>>(X16, W16T, b_f, b_b, xzP);
    // X16 region now dead -> build WhP / WhP8 in it
    k_prep_wh   <<<dim3(2048),      dim3(256),  0, stream>>>(Wh_f, Wh_b, WhP);
    k_prep_wh8  <<<dim3(1536),      dim3(256),  0, stream>>>(Wh_f, Wh_b, WhP8);
    k_recurrence<<<dim3(128),       dim3(512),  0, stream>>>(WhP, WhP8, xzP, hcat16);
    k_gemm_logits<<<dim3(256),      dim3(256),  0, stream>>>(hcat16, WdT16, logits);
    k_softmax   <<<dim3(NROWS / 4), dim3(256),  0, stream>>>(logits, bd, out);
}

// Round 7
// 422.984 us; speedup vs baseline: 1.6333x; 1.0788x over previous
//
#include <hip/hip_runtime.h>
#include <stdint.h>

#define B_    128
#define S_    256
#define EMB_  300
#define HID_  256
#define TAGS_ 50
#define KPAD  320           // EMB padded to multiple of 32
#define NROWS (B_ * S_)     // 32768, row r = s*128 + b
#define GF    (4 * HID_)    // 1024 gate cols per direction
#define NCOLS (2 * GF)      // 2048 (fwd | bwd)

typedef __bf16 bf16x8 __attribute__((ext_vector_type(8)));
typedef float  f32x4  __attribute__((ext_vector_type(4)));
typedef unsigned int u32x4 __attribute__((ext_vector_type(4)));
typedef int    i32x8  __attribute__((ext_vector_type(8)));

__device__ __forceinline__ unsigned short f2bf(float f) {
    unsigned int u = __float_as_uint(f);
    unsigned int r = (u + 0x7fffu + ((u >> 16) & 1u)) >> 16;  // RNE
    return (unsigned short)r;
}
__device__ __forceinline__ bf16x8 ldb8(const unsigned short* p) {
    u32x4 v = *reinterpret_cast<const u32x4*>(p);
    return __builtin_bit_cast(bf16x8, v);
}
// fast sigmoid: v_exp_f32 + v_rcp_f32 (no IEEE div expansion; ~1ulp rcp err)
__device__ __forceinline__ float sigf(float x) {
    return __builtin_amdgcn_rcpf(1.0f + __builtin_amdgcn_exp2f(x * -1.44269504f));
}
// element (p) of an f32x4 pair-slot without dynamic vector indexing
__device__ __forceinline__ float sel2(f32x4 v, int p) {
    return p ? v[1] : v[0];   // rows {p, p+2} hold identical values; take p
}
// async global->LDS, 16B per lane (dest = wave-uniform base + lane*16)
__device__ __forceinline__ void gload_lds16(const void* g, void* l) {
    __builtin_amdgcn_global_load_lds(
        (const __attribute__((address_space(1))) void*)g,
        (__attribute__((address_space(3))) void*)l, 16, 0, 0);
}

// ---------------- K0a: embedding gather -> bf16, K-padded -------------------
__global__ void k_gather_x(const int* __restrict__ tokens, const float* __restrict__ emb,
                           unsigned short* __restrict__ X16) {
    int r = blockIdx.x;            // r = s*128 + b
    int k = threadIdx.x;           // 0..319
    int b = r & 127, s = r >> 7;
    int tok = tokens[b * S_ + s];
    float v = (k < EMB_) ? emb[(long)tok * EMB_ + k] : 0.0f;
    X16[(long)r * KPAD + k] = f2bf(v);
}

// ---------------- K0b: Wx (f|b) -> transposed bf16 [2048][320] --------------
__global__ void k_prep_w(const float* __restrict__ Wx_f, const float* __restrict__ Wx_b,
                         unsigned short* __restrict__ W16T) {
    int c = blockIdx.x;            // 0..2047
    int k = threadIdx.x;           // 0..319
    float v = 0.0f;
    if (k < EMB_) v = (c < GF) ? Wx_f[k * GF + c] : Wx_b[k * GF + (c - GF)];
    W16T[c * KPAD + k] = f2bf(v);
}

// ---------------- K0c: Wd -> transposed bf16 [64][512] ----------------------
__global__ void k_prep_wd(const float* __restrict__ Wd, unsigned short* __restrict__ WdT16) {
    int c = blockIdx.x;            // 0..63
    int k = threadIdx.x;           // 0..511
    float v = (c < TAGS_) ? Wd[k * TAGS_ + c] : 0.0f;
    WdT16[c * 512 + k] = f2bf(v);
}

// ---------------- K0e: Wh ALL 4 gates -> fp8 e4m3 [2 dir][4 g][256 j][256 k]-
// Round-7: g joins the fp8 path (was bf16). Gate order i,f,g,o matches xzP.
__global__ void k_prep_wh8(const float* __restrict__ Wh_f, const float* __restrict__ Wh_b,
                           unsigned char* __restrict__ WhP8) {
    int row = blockIdx.x;          // 0..2047 = (d*4+gi)*256 + j
    int k = threadIdx.x;           // 0..255
    int d = row >> 10, rr = row & 1023, gi = rr >> 8, j = rr & 255;
    const float* Wh = d ? Wh_b : Wh_f;
    float v = Wh[k * GF + gi * HID_ + j];
    int p = __builtin_amdgcn_cvt_pk_fp8_f32(v, 0.0f, 0, false);
    WhP8[(long)row * 256 + k] = (unsigned char)(p & 0xff);
}

// ---------------- K1: xz = X @ Wx + b  (MFMA, LDS-staged, m97 pattern) ------
// 128x128 tile, BK=64, double-buffered LDS, global_load_lds width=16 staging,
// T2 XOR-swizzle j^(row&7) applied on the GLOBAL SOURCE (gload_lds dest is
// linear); ds_read applies the same XOR -> 2 lanes/bank (free). Verified r6.
__global__ __launch_bounds__(256) void k_gemm_xz(
    const unsigned short* __restrict__ X16, const unsigned short* __restrict__ W16T,
    const float* __restrict__ b_f, const float* __restrict__ b_b,
    unsigned long long* __restrict__ xzP) {
    __shared__ __align__(16) unsigned short Asw[2][128 * 64];  // 2 x 16 KB
    __shared__ __align__(16) unsigned short Bsw[2][128 * 64];  // 2 x 16 KB
    int w = threadIdx.x >> 6, lane = threadIdx.x & 63;
    int quad = lane >> 4, l16 = lane & 15;
    int m0 = blockIdx.x * 128;
    int n0 = blockIdx.y * 128;

    int rlane = lane >> 3;                 // 0..7 row within 8-row group
    int jpos  = lane & 7;                  // 16B-chunk position in LDS row
    int jsrc  = jpos ^ (rlane & 7);        // pre-swizzled source chunk

    f32x4 acc[2][8];
#pragma unroll
    for (int mt = 0; mt < 2; ++mt)
#pragma unroll
        for (int nt = 0; nt < 8; ++nt) acc[mt][nt] = (f32x4){0.f, 0.f, 0.f, 0.f};

#define STAGE(ST, BUFI) do {                                                    \
    int k0_ = (ST) * 64;                                                        \
    _Pragma("unroll")                                                           \
    for (int i_ = 0; i_ < 4; ++i_) {                                            \
        int rb_ = (w * 4 + i_) * 8;                                             \
        int r_  = rb_ + rlane;                                                  \
        gload_lds16(X16 + (long)(m0 + r_) * KPAD + k0_ + jsrc * 8,              \
                    &Asw[BUFI][rb_ * 64]);                                      \
    }                                                                           \
    _Pragma("unroll")                                                           \
    for (int i_ = 0; i_ < 4; ++i_) {                                            \
        int rb_ = (w * 4 + i_) * 8;                                             \
        int r_  = rb_ + rlane;                                                  \
        gload_lds16(W16T + (long)(n0 + r_) * KPAD + k0_ + jsrc * 8,             \
                    &Bsw[BUFI][rb_ * 64]);                                      \
    }                                                                           \
} while (0)

    STAGE(0, 0);
    __syncthreads();
#pragma unroll
    for (int st = 0; st < 5; ++st) {       // 5 x BK=64 = KPAD 320
        if (st < 4) STAGE(st + 1, (st + 1) & 1);
        int bufi = st & 1;
#pragma unroll
        for (int ks = 0; ks < 2; ++ks) {
            bf16x8 a[2], bb[8];
#pragma unroll
            for (int mt = 0; mt < 2; ++mt) {
                int mrow = w * 32 + mt * 16 + l16;
                int jp = (ks * 4 + quad) ^ (l16 & 7);
                a[mt] = ldb8(&Asw[bufi][mrow * 64 + jp * 8]);
            }
#pragma unroll
            for (int nt = 0; nt < 8; ++nt) {
                int nrow = nt * 16 + l16;
                int jp = (ks * 4 + quad) ^ (l16 & 7);
                bb[nt] = ldb8(&Bsw[bufi][nrow * 64 + jp * 8]);
            }
#pragma unroll
            for (int mt = 0; mt < 2; ++mt)
#pragma unroll
                for (int nt = 0; nt < 8; ++nt)
                    acc[mt][nt] = __builtin_amdgcn_mfma_f32_16x16x32_bf16(a[mt], bb[nt], acc[mt][nt], 0, 0, 0);
        }
        __syncthreads();
    }
#undef STAGE

    int s = blockIdx.x;            // m>>7
#pragma unroll
    for (int mt = 0; mt < 2; ++mt) {
        int grp = w * 2 + mt;      // (b>>4)
#pragma unroll
        for (int nt = 0; nt < 8; ++nt) {
            int col = n0 + nt * 16 + l16;
            int dir = col >> 10, cc = col & 1023;
            int gate = cc >> 8, u16 = (cc & 255) >> 4;
            float bias = dir ? b_b[cc] : b_f[cc];
            unsigned long long pk = 0;
#pragma unroll
            for (int r = 0; r < 4; ++r)
                pk |= (unsigned long long)f2bf(acc[mt][nt][r] + bias) << (16 * r);
            long idx8 = ((long)(s * 16 + dir * 8 + grp)) * 4096 +
                        (gate * 16 + u16) * 64 + quad * 16 + l16;
            xzP[idx8] = pk;
        }
    }
}

// ---------------- K2: bidirectional LSTM recurrence, single-CU chains -------
// r3 structure (verified 242-245us twice) with the g gate moved to the fp8
// scaled-MFMA path (round-7). Per-wave MFMA: 16 scaled K=128 (4 gates x 2 cg
// x 2 kt2), ZERO bf16 MFMA -> per-SIMD issue 1104 cyc (was 1449). The bf16
// Wh pipeline (WhP, whg fragments, 8 ds_read_b128/step, h bf16 LDS buffer)
// is deleted: -64 pinned VGPR, conflicts ~halved, LDS 3584 -> 1152 B.
// h is ALREADY fp8-quantized for i/f/o; g now reads the same quantized h
// (sensitivity ~ f-gate path, which passes) — absmax is the watch item.
__global__ __launch_bounds__(512, 2) void k_recurrence(
    const unsigned char* __restrict__ WhP8,
    const unsigned long long* __restrict__ xzP, unsigned short* __restrict__ hcat16) {
    __shared__ __align__(16) unsigned char lds[1152];  // h8: 2 buf x 2 par x 288 B
    int tid = threadIdx.x;
    int w = tid >> 6, lane = tid & 63, quad = lane >> 4, l16 = lane & 15;
    int blk = blockIdx.x;
    int d = blk >> 6, bg2 = blk & 63;           // batch pair b0 = bg2*2
    int p = quad & 1;                            // lane's batch parity
    int cg = quad >> 1;                          // lane's colgroup (0/1)
    int col = 16 * (2 * w + cg) + l16;           // lane's cell column
    int rp = l16 & 1;                            // A-row parity of this lane's row

    // all-gate fp8 K=128 scaled-MFMA B fragments, register-pinned (128 VGPR)
    i32x8 wh8s[4][2][2];
#pragma unroll
    for (int gi = 0; gi < 4; ++gi)
#pragma unroll
        for (int cgi = 0; cgi < 2; ++cgi)
#pragma unroll
            for (int kt2 = 0; kt2 < 2; ++kt2) {
                const unsigned char* wp8 = WhP8 +
                    ((long)((d * 4 + gi) * 256 + 16 * (2 * w + cgi) + l16)) * 256 +
                    kt2 * 128 + quad * 32;
                i32x8 v = *reinterpret_cast<const i32x8*>(wp8);
                asm volatile("" : "+v"(v));
                wh8s[gi][cgi][kt2] = v;
            }

    float c2 = 0.f;

    // xz addressing: u16 index = (s*16 + rowc)*16384 + ga*4096 + laneoff
    const unsigned short* xzU = (const unsigned short*)xzP;
    int rowc = d * 8 + (bg2 >> 3);
    unsigned int laneoff = (unsigned)((2 * w + cg) * 256 +
                                      (((bg2 >> 1) & 3) * 16 + l16) * 4 +
                                      2 * (bg2 & 1) + p);

    // preload xz for first step (4 ushorts per lane: gates i,f,g,o)
    unsigned short xzu[4];
    {
        int s0 = d ? 255 : 0;
        const unsigned short* ps = xzU + (unsigned long)(s0 * 16 + rowc) * 16384;
#pragma unroll
        for (int ga = 0; ga < 4; ++ga) xzu[ga] = ps[laneoff + ga * 4096];
    }

    for (int t = 0; t < 256; ++t) {
        int s = d ? (255 - t) : t;
        int pb = t & 1, cb = pb ^ 1;
        f32x4 acc8[4][2];
#pragma unroll
        for (int gi = 0; gi < 4; ++gi)
#pragma unroll
            for (int cgi = 0; cgi < 2; ++cgi) acc8[gi][cgi] = (f32x4){0.f, 0.f, 0.f, 0.f};

        if (t > 0) {
#pragma unroll
            for (int kt2 = 0; kt2 < 2; ++kt2) {
                i32x8 A8 = *reinterpret_cast<const i32x8*>(
                    lds + cb * 576 + rp * 288 + kt2 * 128 + quad * 32);
#pragma unroll
                for (int cgi = 0; cgi < 2; ++cgi)
#pragma unroll
                    for (int gi = 0; gi < 4; ++gi)
#if __has_builtin(__builtin_amdgcn_mfma_scale_f32_16x16x128_f8f6f4)
                        acc8[gi][cgi] = __builtin_amdgcn_mfma_scale_f32_16x16x128_f8f6f4(
                            A8, wh8s[gi][cgi][kt2], acc8[gi][cgi], 0, 0, 0, 0x7F, 0, 0x7F);
#else
                        acc8[gi][cgi] = acc8[gi][cgi];  // unreachable on gfx950
#endif
            }
        }
        // extract current-step xz addends (bf16 -> f32 is one shl each)
        float xa0 = __uint_as_float((unsigned int)xzu[0] << 16);
        float xa1 = __uint_as_float((unsigned int)xzu[1] << 16);
        float xa2 = __uint_as_float((unsigned int)xzu[2] << 16);
        float xa3 = __uint_as_float((unsigned int)xzu[3] << 16);
        // prefetch next step (fire-and-forget; consumed after next barrier)
        {
            int sn = d ? (s ? s - 1 : 0) : (s < 255 ? s + 1 : 255);
            const unsigned short* ps = xzU + (unsigned long)(sn * 16 + rowc) * 16384;
#pragma unroll
            for (int ga = 0; ga < 4; ++ga) xzu[ga] = ps[laneoff + ga * 4096];
        }
        // gates: lane's cell (batch bg2*2+p, col). C row m=quad*4+r has batch
        // m&1=r&1 -> element p (== element p+2). Colgroup pick by cg.
        float zi = (cg ? sel2(acc8[0][1], p) : sel2(acc8[0][0], p)) + xa0;
        float zf = (cg ? sel2(acc8[1][1], p) : sel2(acc8[1][0], p)) + xa1;
        float zg = (cg ? sel2(acc8[2][1], p) : sel2(acc8[2][0], p)) + xa2;
        float zo = (cg ? sel2(acc8[3][1], p) : sel2(acc8[3][0], p)) + xa3;
        float c = sigf(zf) * c2 + sigf(zi) * fmaxf(zg, 0.0f);
        c2 = c;
        float h = sigf(zo) * fmaxf(c, 0.0f);

        int p8 = __builtin_amdgcn_cvt_pk_fp8_f32(h, h, 0, false);
        *(lds + pb * 576 + p * 288 + col) = (unsigned char)(p8 & 0xff);
        // hcat direct from register (fire-and-forget; barrier won't drain it)
        hcat16[((long)(bg2 * 2 + p) * S_ + s) * 512 + d * HID_ + col] = f2bf(h);
        // LDS-only barrier: no vmcnt drain (global stores/loads stay in flight)
        asm volatile("s_waitcnt lgkmcnt(0)\n\ts_barrier" ::: "memory");
    }
}

// ---------------- K3: logits = hcat @ Wd, +bd, fused softmax -> out ---------
// Round-7: K4 folded into the epilogue. Each output row's 64 cols live in the
// 16 lanes of one quad-group x 4 acc entries -> softmax = 2 x 4 shfl_xor +
// in-register exp; saves the logits round-trip and one launch.
__global__ __launch_bounds__(256) void k_gemm_logits(
    const unsigned short* __restrict__ hcat16, const unsigned short* __restrict__ WdT16,
    const float* __restrict__ bd, float* __restrict__ out) {
    int w = threadIdx.x >> 6, lane = threadIdx.x & 63;
    int quad = lane >> 4, l16 = lane & 15;
    int m0 = blockIdx.x * 128 + w * 32;
    f32x4 acc[2][4];
#pragma unroll
    for (int mt = 0; mt < 2; ++mt)
#pragma unroll
        for (int nt = 0; nt < 4; ++nt) acc[mt][nt] = (f32x4){0.f, 0.f, 0.f, 0.f};
#pragma unroll
    for (int ks = 0; ks < 16; ++ks) {
        int k0 = ks * 32 + quad * 8;
        bf16x8 a[2], bb[4];
#pragma unroll
        for (int mt = 0; mt < 2; ++mt)
            a[mt] = ldb8(hcat16 + (long)(m0 + mt * 16 + l16) * 512 + k0);
#pragma unroll
        for (int nt = 0; nt < 4; ++nt)
            bb[nt] = ldb8(WdT16 + (long)(nt * 16 + l16) * 512 + k0);
#pragma unroll
        for (int mt = 0; mt < 2; ++mt)
#pragma unroll
            for (int nt = 0; nt < 4; ++nt)
                acc[mt][nt] = __builtin_amdgcn_mfma_f32_16x16x32_bf16(a[mt], bb[nt], acc[mt][nt], 0, 0, 0);
    }
#pragma unroll
    for (int mt = 0; mt < 2; ++mt) {
#pragma unroll
        for (int r = 0; r < 4; ++r) {
            int row = m0 + mt * 16 + quad * 4 + r;
            float vv[4];
            float mx = -3.0e38f;
#pragma unroll
            for (int nt = 0; nt < 4; ++nt) {
                int cl = nt * 16 + l16;
                float tv = (cl < TAGS_) ? (acc[mt][nt][r] + bd[cl]) : -3.0e38f;
                vv[nt] = tv;
                mx = fmaxf(mx, tv);
            }
#pragma unroll
            for (int off = 8; off >= 1; off >>= 1) mx = fmaxf(mx, __shfl_xor(mx, off, 64));
            float sum = 0.f;
#pragma unroll
            for (int nt = 0; nt < 4; ++nt) {
                int cl = nt * 16 + l16;
                float e = (cl < TAGS_) ? __expf(vv[nt] - mx) : 0.0f;
                vv[nt] = e;
                sum += e;
            }
#pragma unroll
            for (int off = 8; off >= 1; off >>= 1) sum += __shfl_xor(sum, off, 64);
            float rs = __builtin_amdgcn_rcpf(sum);
#pragma unroll
            for (int nt = 0; nt < 4; ++nt) {
                int cl = nt * 16 + l16;
                if (cl < TAGS_) out[(long)row * TAGS_ + cl] = vv[nt] * rs;
            }
        }
    }
}

extern "C" void kernel_launch(void* const* d_in, const int* in_sizes, int n_in,
                              void* d_out, int out_size, void* d_ws, size_t ws_size,
                              hipStream_t stream) {
    (void)in_sizes; (void)n_in; (void)out_size; (void)ws_size;
    const int*   tokens = (const int*)  d_in[0];
    const float* emb    = (const float*)d_in[1];
    const float* Wx_f   = (const float*)d_in[2];
    const float* Wh_f   = (const float*)d_in[3];
    const float* b_f    = (const float*)d_in[4];
    const float* Wx_b   = (const float*)d_in[5];
    const float* Wh_b   = (const float*)d_in[6];
    const float* b_b    = (const float*)d_in[7];
    const float* Wd     = (const float*)d_in[8];
    const float* bd     = (const float*)d_in[9];
    float* out = (float*)d_out;

    // workspace layout (bytes): total 190,119,936
    uint8_t* w = (uint8_t*)d_ws;
    unsigned short* X16    = (unsigned short*)(w);                  // 20,971,520 (dead after K1)
    // alias inside X16's region, used only after K1:
    unsigned char*  WhP8   = (unsigned char*)(w);                   //    524,288
    unsigned short* W16T   = (unsigned short*)(w + 20971520);       //  1,310,720
    unsigned short* WdT16  = (unsigned short*)(w + 22282240);       //     65,536
    unsigned long long* xzP = (unsigned long long*)(w + 22347776);  // 134,217,728
    unsigned short* hcat16 = (unsigned short*)(w + 156565504);      //  33,554,432

    k_gather_x  <<<dim3(NROWS),     dim3(KPAD), 0, stream>>>(tokens, emb, X16);
    k_prep_w    <<<dim3(NCOLS),     dim3(KPAD), 0, stream>>>(Wx_f, Wx_b, W16T);
    k_prep_wd   <<<dim3(64),        dim3(512),  0, stream>>>(Wd, WdT16);
    k_gemm_xz   <<<dim3(256, 16),   dim3(256),  0, stream>>>(X16, W16T, b_f, b_b, xzP);
    // X16 region now dead -> build WhP8 in it (all 4 gates, fp8)
    k_prep_wh8  <<<dim3(2048),      dim3(256),  0, stream>>>(Wh_f, Wh_b, WhP8);
    k_recurrence<<<dim3(128),       dim3(512),  0, stream>>>(WhP8, xzP, hcat16);
    k_gemm_logits<<<dim3(256),      dim3(256),  0, stream>>>(hcat16, WdT16, bd, out);
}

// Round 8
// 412.868 us; speedup vs baseline: 1.6733x; 1.0245x over previous
//
#include <hip/hip_runtime.h>
#include <stdint.h>

#define B_    128
#define S_    256
#define EMB_  300
#define HID_  256
#define TAGS_ 50
#define KPAD  320           // EMB padded to multiple of 32
#define NROWS (B_ * S_)     // 32768, row r = s*128 + b
#define GF    (4 * HID_)    // 1024 gate cols per direction
#define NCOLS (2 * GF)      // 2048 (fwd | bwd)

typedef __bf16 bf16x8 __attribute__((ext_vector_type(8)));
typedef float  f32x4  __attribute__((ext_vector_type(4)));
typedef unsigned int u32x4 __attribute__((ext_vector_type(4)));
typedef int    i32x8  __attribute__((ext_vector_type(8)));

__device__ __forceinline__ unsigned short f2bf(float f) {
    unsigned int u = __float_as_uint(f);
    unsigned int r = (u + 0x7fffu + ((u >> 16) & 1u)) >> 16;  // RNE
    return (unsigned short)r;
}
__device__ __forceinline__ bf16x8 ldb8(const unsigned short* p) {
    u32x4 v = *reinterpret_cast<const u32x4*>(p);
    return __builtin_bit_cast(bf16x8, v);
}
// fast sigmoid: v_exp_f32 + v_rcp_f32 (no IEEE div expansion; ~1ulp rcp err)
__device__ __forceinline__ float sigf(float x) {
    return __builtin_amdgcn_rcpf(1.0f + __builtin_amdgcn_exp2f(x * -1.44269504f));
}
// element (p) of an f32x4 pair-slot without dynamic vector indexing
__device__ __forceinline__ float sel2(f32x4 v, int p) {
    return p ? v[1] : v[0];   // rows {p, p+2} hold identical values; take p
}
// async global->LDS, 16B per lane (dest = wave-uniform base + lane*16)
__device__ __forceinline__ void gload_lds16(const void* g, void* l) {
    __builtin_amdgcn_global_load_lds(
        (const __attribute__((address_space(1))) void*)g,
        (__attribute__((address_space(3))) void*)l, 16, 0, 0);
}

// ---------------- K0: merged prep (gather | Wx transpose | Wd transpose) ----
// Region 0: 32768 blocks -> embedding gather (bf16, K-padded)
// Region 1:  2048 blocks -> Wx (f|b) transposed bf16 [2048][320]
// Region 2:   103 blocks -> Wd transposed bf16 [64][512], flat-indexed
// (prep_wh8 canNOT merge here: WhP8 aliases X16's region, written after K1.)
__global__ void k_prep_all(const int* __restrict__ tokens, const float* __restrict__ emb,
                           const float* __restrict__ Wx_f, const float* __restrict__ Wx_b,
                           const float* __restrict__ Wd,
                           unsigned short* __restrict__ X16,
                           unsigned short* __restrict__ W16T,
                           unsigned short* __restrict__ WdT16) {
    int blk = blockIdx.x, k = threadIdx.x;           // k: 0..319
    if (blk < NROWS) {                               // gather: r = s*128 + b
        int b = blk & 127, s = blk >> 7;
        int tok = tokens[b * S_ + s];
        float v = (k < EMB_) ? emb[(long)tok * EMB_ + k] : 0.0f;
        X16[(long)blk * KPAD + k] = f2bf(v);
    } else if (blk < NROWS + NCOLS) {                // Wx transpose
        int c = blk - NROWS;
        float v = 0.0f;
        if (k < EMB_) v = (c < GF) ? Wx_f[k * GF + c] : Wx_b[k * GF + (c - GF)];
        W16T[c * KPAD + k] = f2bf(v);
    } else {                                         // Wd transpose, flat
        int e = (blk - NROWS - NCOLS) * 320 + k;     // 0..32959; valid < 32768
        if (e < 64 * 512) {
            int c = e >> 9, kk = e & 511;
            float v = (c < TAGS_) ? Wd[kk * TAGS_ + c] : 0.0f;
            WdT16[c * 512 + kk] = f2bf(v);
        }
    }
}

// ---------------- K0e: Wh ALL 4 gates -> fp8 e4m3 [2 dir][4 g][256 j][256 k]-
// Runs after K1 (WhP8 aliases the then-dead X16 region).
__global__ void k_prep_wh8(const float* __restrict__ Wh_f, const float* __restrict__ Wh_b,
                           unsigned char* __restrict__ WhP8) {
    int row = blockIdx.x;          // 0..2047 = (d*4+gi)*256 + j
    int k = threadIdx.x;           // 0..255
    int d = row >> 10, rr = row & 1023, gi = rr >> 8, j = rr & 255;
    const float* Wh = d ? Wh_b : Wh_f;
    float v = Wh[k * GF + gi * HID_ + j];
    int p = __builtin_amdgcn_cvt_pk_fp8_f32(v, 0.0f, 0, false);
    WhP8[(long)row * 256 + k] = (unsigned char)(p & 0xff);
}

// ---------------- K1: xz = X @ Wx + b  (MFMA, LDS-staged, m97 pattern) ------
// 128x128 tile, BK=64, double-buffered LDS, global_load_lds width=16 staging,
// T2 XOR-swizzle j^(row&7) applied on the GLOBAL SOURCE (gload_lds dest is
// linear); ds_read applies the same XOR -> 2 lanes/bank (free). Verified r6.
__global__ __launch_bounds__(256) void k_gemm_xz(
    const unsigned short* __restrict__ X16, const unsigned short* __restrict__ W16T,
    const float* __restrict__ b_f, const float* __restrict__ b_b,
    unsigned long long* __restrict__ xzP) {
    __shared__ __align__(16) unsigned short Asw[2][128 * 64];  // 2 x 16 KB
    __shared__ __align__(16) unsigned short Bsw[2][128 * 64];  // 2 x 16 KB
    int w = threadIdx.x >> 6, lane = threadIdx.x & 63;
    int quad = lane >> 4, l16 = lane & 15;
    int m0 = blockIdx.x * 128;
    int n0 = blockIdx.y * 128;

    int rlane = lane >> 3;                 // 0..7 row within 8-row group
    int jpos  = lane & 7;                  // 16B-chunk position in LDS row
    int jsrc  = jpos ^ (rlane & 7);        // pre-swizzled source chunk

    f32x4 acc[2][8];
#pragma unroll
    for (int mt = 0; mt < 2; ++mt)
#pragma unroll
        for (int nt = 0; nt < 8; ++nt) acc[mt][nt] = (f32x4){0.f, 0.f, 0.f, 0.f};

#define STAGE(ST, BUFI) do {                                                    \
    int k0_ = (ST) * 64;                                                        \
    _Pragma("unroll")                                                           \
    for (int i_ = 0; i_ < 4; ++i_) {                                            \
        int rb_ = (w * 4 + i_) * 8;                                             \
        int r_  = rb_ + rlane;                                                  \
        gload_lds16(X16 + (long)(m0 + r_) * KPAD + k0_ + jsrc * 8,              \
                    &Asw[BUFI][rb_ * 64]);                                      \
    }                                                                           \
    _Pragma("unroll")                                                           \
    for (int i_ = 0; i_ < 4; ++i_) {                                            \
        int rb_ = (w * 4 + i_) * 8;                                             \
        int r_  = rb_ + rlane;                                                  \
        gload_lds16(W16T + (long)(n0 + r_) * KPAD + k0_ + jsrc * 8,             \
                    &Bsw[BUFI][rb_ * 64]);                                      \
    }                                                                           \
} while (0)

    STAGE(0, 0);
    __syncthreads();
#pragma unroll
    for (int st = 0; st < 5; ++st) {       // 5 x BK=64 = KPAD 320
        if (st < 4) STAGE(st + 1, (st + 1) & 1);
        int bufi = st & 1;
#pragma unroll
        for (int ks = 0; ks < 2; ++ks) {
            bf16x8 a[2], bb[8];
#pragma unroll
            for (int mt = 0; mt < 2; ++mt) {
                int mrow = w * 32 + mt * 16 + l16;
                int jp = (ks * 4 + quad) ^ (l16 & 7);
                a[mt] = ldb8(&Asw[bufi][mrow * 64 + jp * 8]);
            }
#pragma unroll
            for (int nt = 0; nt < 8; ++nt) {
                int nrow = nt * 16 + l16;
                int jp = (ks * 4 + quad) ^ (l16 & 7);
                bb[nt] = ldb8(&Bsw[bufi][nrow * 64 + jp * 8]);
            }
#pragma unroll
            for (int mt = 0; mt < 2; ++mt)
#pragma unroll
                for (int nt = 0; nt < 8; ++nt)
                    acc[mt][nt] = __builtin_amdgcn_mfma_f32_16x16x32_bf16(a[mt], bb[nt], acc[mt][nt], 0, 0, 0);
        }
        __syncthreads();
    }
#undef STAGE

    int s = blockIdx.x;            // m>>7
#pragma unroll
    for (int mt = 0; mt < 2; ++mt) {
        int grp = w * 2 + mt;      // (b>>4)
#pragma unroll
        for (int nt = 0; nt < 8; ++nt) {
            int col = n0 + nt * 16 + l16;
            int dir = col >> 10, cc = col & 1023;
            int gate = cc >> 8, u16 = (cc & 255) >> 4;
            float bias = dir ? b_b[cc] : b_f[cc];
            unsigned long long pk = 0;
#pragma unroll
            for (int r = 0; r < 4; ++r)
                pk |= (unsigned long long)f2bf(acc[mt][nt][r] + bias) << (16 * r);
            long idx8 = ((long)(s * 16 + dir * 8 + grp)) * 4096 +
                        (gate * 16 + u16) * 64 + quad * 16 + l16;
            xzP[idx8] = pk;
        }
    }
}

// ---------------- K2: bidirectional LSTM recurrence, single-CU chains -------
// r3 structure + all-fp8 gates (verified r7: 212us, absmax unchanged).
// step ~1990 cyc = 1104 MFMA-issue (16 scaled K=128 per wave x 34.5/SIMD)
// + ~750 VALU + ~220 stall/conflict. Untouched this round (control).
__global__ __launch_bounds__(512, 2) void k_recurrence(
    const unsigned char* __restrict__ WhP8,
    const unsigned long long* __restrict__ xzP, unsigned short* __restrict__ hcat16) {
    __shared__ __align__(16) unsigned char lds[1152];  // h8: 2 buf x 2 par x 288 B
    int tid = threadIdx.x;
    int w = tid >> 6, lane = tid & 63, quad = lane >> 4, l16 = lane & 15;
    int blk = blockIdx.x;
    int d = blk >> 6, bg2 = blk & 63;           // batch pair b0 = bg2*2
    int p = quad & 1;                            // lane's batch parity
    int cg = quad >> 1;                          // lane's colgroup (0/1)
    int col = 16 * (2 * w + cg) + l16;           // lane's cell column
    int rp = l16 & 1;                            // A-row parity of this lane's row

    // all-gate fp8 K=128 scaled-MFMA B fragments, register-pinned (128 VGPR)
    i32x8 wh8s[4][2][2];
#pragma unroll
    for (int gi = 0; gi < 4; ++gi)
#pragma unroll
        for (int cgi = 0; cgi < 2; ++cgi)
#pragma unroll
            for (int kt2 = 0; kt2 < 2; ++kt2) {
                const unsigned char* wp8 = WhP8 +
                    ((long)((d * 4 + gi) * 256 + 16 * (2 * w + cgi) + l16)) * 256 +
                    kt2 * 128 + quad * 32;
                i32x8 v = *reinterpret_cast<const i32x8*>(wp8);
                asm volatile("" : "+v"(v));
                wh8s[gi][cgi][kt2] = v;
            }

    float c2 = 0.f;

    // xz addressing: u16 index = (s*16 + rowc)*16384 + ga*4096 + laneoff
    const unsigned short* xzU = (const unsigned short*)xzP;
    int rowc = d * 8 + (bg2 >> 3);
    unsigned int laneoff = (unsigned)((2 * w + cg) * 256 +
                                      (((bg2 >> 1) & 3) * 16 + l16) * 4 +
                                      2 * (bg2 & 1) + p);

    // preload xz for first step (4 ushorts per lane: gates i,f,g,o)
    unsigned short xzu[4];
    {
        int s0 = d ? 255 : 0;
        const unsigned short* ps = xzU + (unsigned long)(s0 * 16 + rowc) * 16384;
#pragma unroll
        for (int ga = 0; ga < 4; ++ga) xzu[ga] = ps[laneoff + ga * 4096];
    }

    for (int t = 0; t < 256; ++t) {
        int s = d ? (255 - t) : t;
        int pb = t & 1, cb = pb ^ 1;
        f32x4 acc8[4][2];
#pragma unroll
        for (int gi = 0; gi < 4; ++gi)
#pragma unroll
            for (int cgi = 0; cgi < 2; ++cgi) acc8[gi][cgi] = (f32x4){0.f, 0.f, 0.f, 0.f};

        if (t > 0) {
#pragma unroll
            for (int kt2 = 0; kt2 < 2; ++kt2) {
                i32x8 A8 = *reinterpret_cast<const i32x8*>(
                    lds + cb * 576 + rp * 288 + kt2 * 128 + quad * 32);
#pragma unroll
                for (int cgi = 0; cgi < 2; ++cgi)
#pragma unroll
                    for (int gi = 0; gi < 4; ++gi)
#if __has_builtin(__builtin_amdgcn_mfma_scale_f32_16x16x128_f8f6f4)
                        acc8[gi][cgi] = __builtin_amdgcn_mfma_scale_f32_16x16x128_f8f6f4(
                            A8, wh8s[gi][cgi][kt2], acc8[gi][cgi], 0, 0, 0, 0x7F, 0, 0x7F);
#else
                        acc8[gi][cgi] = acc8[gi][cgi];  // unreachable on gfx950
#endif
            }
        }
        // extract current-step xz addends (bf16 -> f32 is one shl each)
        float xa0 = __uint_as_float((unsigned int)xzu[0] << 16);
        float xa1 = __uint_as_float((unsigned int)xzu[1] << 16);
        float xa2 = __uint_as_float((unsigned int)xzu[2] << 16);
        float xa3 = __uint_as_float((unsigned int)xzu[3] << 16);
        // prefetch next step (fire-and-forget; consumed after next barrier)
        {
            int sn = d ? (s ? s - 1 : 0) : (s < 255 ? s + 1 : 255);
            const unsigned short* ps = xzU + (unsigned long)(sn * 16 + rowc) * 16384;
#pragma unroll
            for (int ga = 0; ga < 4; ++ga) xzu[ga] = ps[laneoff + ga * 4096];
        }
        // gates: lane's cell (batch bg2*2+p, col). C row m=quad*4+r has batch
        // m&1=r&1 -> element p (== element p+2). Colgroup pick by cg.
        float zi = (cg ? sel2(acc8[0][1], p) : sel2(acc8[0][0], p)) + xa0;
        float zf = (cg ? sel2(acc8[1][1], p) : sel2(acc8[1][0], p)) + xa1;
        float zg = (cg ? sel2(acc8[2][1], p) : sel2(acc8[2][0], p)) + xa2;
        float zo = (cg ? sel2(acc8[3][1], p) : sel2(acc8[3][0], p)) + xa3;
        float c = sigf(zf) * c2 + sigf(zi) * fmaxf(zg, 0.0f);
        c2 = c;
        float h = sigf(zo) * fmaxf(c, 0.0f);

        int p8 = __builtin_amdgcn_cvt_pk_fp8_f32(h, h, 0, false);
        *(lds + pb * 576 + p * 288 + col) = (unsigned char)(p8 & 0xff);
        // hcat direct from register (fire-and-forget; barrier won't drain it)
        hcat16[((long)(bg2 * 2 + p) * S_ + s) * 512 + d * HID_ + col] = f2bf(h);
        // LDS-only barrier: no vmcnt drain (global stores/loads stay in flight)
        asm volatile("s_waitcnt lgkmcnt(0)\n\ts_barrier" ::: "memory");
    }
}

// ---------------- K3: logits = hcat @ Wd, +bd, fused softmax -> out ---------
// Round-8: LDS-staged like K1 (same verified tile geometry: A [128][64] bf16
// chunks, XOR-swizzle on global source, ds_read_b128 with matching XOR).
// B (WdT) [64][64] chunks. 8 K-chunks of 64 over K=512, double-buffered.
// Epilogue (fused softmax) unchanged from verified r7.
__global__ __launch_bounds__(256) void k_gemm_logits(
    const unsigned short* __restrict__ hcat16, const unsigned short* __restrict__ WdT16,
    const float* __restrict__ bd, float* __restrict__ out) {
    __shared__ __align__(16) unsigned short Asw[2][128 * 64];  // 2 x 16 KB
    __shared__ __align__(16) unsigned short Bsw[2][64 * 64];   // 2 x 8 KB
    int w = threadIdx.x >> 6, lane = threadIdx.x & 63;
    int quad = lane >> 4, l16 = lane & 15;
    int m0 = blockIdx.x * 128;
    int rlane = lane >> 3, jpos = lane & 7;
    int jsrc = jpos ^ (rlane & 7);

    f32x4 acc[2][4];
#pragma unroll
    for (int mt = 0; mt < 2; ++mt)
#pragma unroll
        for (int nt = 0; nt < 4; ++nt) acc[mt][nt] = (f32x4){0.f, 0.f, 0.f, 0.f};

#define STAGE3(ST, BUFI) do {                                                   \
    int k0_ = (ST) * 64;                                                        \
    _Pragma("unroll")                                                           \
    for (int i_ = 0; i_ < 4; ++i_) {                                            \
        int rb_ = (w * 4 + i_) * 8;                                             \
        int r_  = rb_ + rlane;                                                  \
        gload_lds16(hcat16 + (long)(m0 + r_) * 512 + k0_ + jsrc * 8,            \
                    &Asw[BUFI][rb_ * 64]);                                      \
    }                                                                           \
    _Pragma("unroll")                                                           \
    for (int i_ = 0; i_ < 2; ++i_) {                                            \
        int rb_ = (w * 2 + i_) * 8;                                             \
        int r_  = rb_ + rlane;                                                  \
        gload_lds16(WdT16 + (long)r_ * 512 + k0_ + jsrc * 8,                    \
                    &Bsw[BUFI][rb_ * 64]);                                      \
    }                                                                           \
} while (0)

    STAGE3(0, 0);
    __syncthreads();
#pragma unroll
    for (int st = 0; st < 8; ++st) {       // 8 x BK=64 = K 512
        if (st < 7) STAGE3(st + 1, (st + 1) & 1);
        int bufi = st & 1;
#pragma unroll
        for (int ks = 0; ks < 2; ++ks) {
            bf16x8 a[2], bb[4];
#pragma unroll
            for (int mt = 0; mt < 2; ++mt) {
                int mrow = w * 32 + mt * 16 + l16;
                int jp = (ks * 4 + quad) ^ (l16 & 7);
                a[mt] = ldb8(&Asw[bufi][mrow * 64 + jp * 8]);
            }
#pragma unroll
            for (int nt = 0; nt < 4; ++nt) {
                int nrow = nt * 16 + l16;
                int jp = (ks * 4 + quad) ^ (l16 & 7);
                bb[nt] = ldb8(&Bsw[bufi][nrow * 64 + jp * 8]);
            }
#pragma unroll
            for (int mt = 0; mt < 2; ++mt)
#pragma unroll
                for (int nt = 0; nt < 4; ++nt)
                    acc[mt][nt] = __builtin_amdgcn_mfma_f32_16x16x32_bf16(a[mt], bb[nt], acc[mt][nt], 0, 0, 0);
        }
        __syncthreads();
    }
#undef STAGE3

#pragma unroll
    for (int mt = 0; mt < 2; ++mt) {
#pragma unroll
        for (int r = 0; r < 4; ++r) {
            int row = m0 + w * 32 + mt * 16 + quad * 4 + r;
            float vv[4];
            float mx = -3.0e38f;
#pragma unroll
            for (int nt = 0; nt < 4; ++nt) {
                int cl = nt * 16 + l16;
                float tv = (cl < TAGS_) ? (acc[mt][nt][r] + bd[cl]) : -3.0e38f;
                vv[nt] = tv;
                mx = fmaxf(mx, tv);
            }
#pragma unroll
            for (int off = 8; off >= 1; off >>= 1) mx = fmaxf(mx, __shfl_xor(mx, off, 64));
            float sum = 0.f;
#pragma unroll
            for (int nt = 0; nt < 4; ++nt) {
                int cl = nt * 16 + l16;
                float e = (cl < TAGS_) ? __expf(vv[nt] - mx) : 0.0f;
                vv[nt] = e;
                sum += e;
            }
#pragma unroll
            for (int off = 8; off >= 1; off >>= 1) sum += __shfl_xor(sum, off, 64);
            float rs = __builtin_amdgcn_rcpf(sum);
#pragma unroll
            for (int nt = 0; nt < 4; ++nt) {
                int cl = nt * 16 + l16;
                if (cl < TAGS_) out[(long)row * TAGS_ + cl] = vv[nt] * rs;
            }
        }
    }
}

extern "C" void kernel_launch(void* const* d_in, const int* in_sizes, int n_in,
                              void* d_out, int out_size, void* d_ws, size_t ws_size,
                              hipStream_t stream) {
    (void)in_sizes; (void)n_in; (void)out_size; (void)ws_size;
    const int*   tokens = (const int*)  d_in[0];
    const float* emb    = (const float*)d_in[1];
    const float* Wx_f   = (const float*)d_in[2];
    const float* Wh_f   = (const float*)d_in[3];
    const float* b_f    = (const float*)d_in[4];
    const float* Wx_b   = (const float*)d_in[5];
    const float* Wh_b   = (const float*)d_in[6];
    const float* b_b    = (const float*)d_in[7];
    const float* Wd     = (const float*)d_in[8];
    const float* bd     = (const float*)d_in[9];
    float* out = (float*)d_out;

    // workspace layout (bytes): total 190,119,936
    uint8_t* w = (uint8_t*)d_ws;
    unsigned short* X16    = (unsigned short*)(w);                  // 20,971,520 (dead after K1)
    // alias inside X16's region, used only after K1:
    unsigned char*  WhP8   = (unsigned char*)(w);                   //    524,288
    unsigned short* W16T   = (unsigned short*)(w + 20971520);       //  1,310,720
    unsigned short* WdT16  = (unsigned short*)(w + 22282240);       //     65,536
    unsigned long long* xzP = (unsigned long long*)(w + 22347776);  // 134,217,728
    unsigned short* hcat16 = (unsigned short*)(w + 156565504);      //  33,554,432

    // merged prep: gather (32768) | Wx-T (2048) | Wd-T (103 flat blocks)
    k_prep_all  <<<dim3(NROWS + NCOLS + 103), dim3(KPAD), 0, stream>>>(
        tokens, emb, Wx_f, Wx_b, Wd, X16, W16T, WdT16);
    k_gemm_xz   <<<dim3(256, 16),   dim3(256),  0, stream>>>(X16, W16T, b_f, b_b, xzP);
    // X16 region now dead -> build WhP8 in it (all 4 gates, fp8)
    k_prep_wh8  <<<dim3(2048),      dim3(256),  0, stream>>>(Wh_f, Wh_b, WhP8);
    k_recurrence<<<dim3(128),       dim3(512),  0, stream>>>(WhP8, xzP, hcat16);
    k_gemm_logits<<<dim3(256),      dim3(256),  0, stream>>>(hcat16, WdT16, bd, out);
}

// Round 9
// 401.716 us; speedup vs baseline: 1.7197x; 1.0278x over previous
//
#include <hip/hip_runtime.h>
#include <stdint.h>

#define B_    128
#define S_    256
#define EMB_  300
#define HID_  256
#define TAGS_ 50
#define KP8   384           // EMB padded to multiple of 128 (fp8 K1 path)
#define NROWS (B_ * S_)     // 32768, row r = s*128 + b
#define GF    (4 * HID_)    // 1024 gate cols per direction
#define NCOLS (2 * GF)      // 2048 (fwd | bwd)

typedef __bf16 bf16x8 __attribute__((ext_vector_type(8)));
typedef float  f32x4  __attribute__((ext_vector_type(4)));
typedef unsigned int u32x4 __attribute__((ext_vector_type(4)));
typedef int    i32x8  __attribute__((ext_vector_type(8)));

__device__ __forceinline__ unsigned short f2bf(float f) {
    unsigned int u = __float_as_uint(f);
    unsigned int r = (u + 0x7fffu + ((u >> 16) & 1u)) >> 16;  // RNE
    return (unsigned short)r;
}
__device__ __forceinline__ bf16x8 ldb8(const unsigned short* p) {
    u32x4 v = *reinterpret_cast<const u32x4*>(p);
    return __builtin_bit_cast(bf16x8, v);
}
__device__ __forceinline__ unsigned char f2fp8(float v) {
    int p = __builtin_amdgcn_cvt_pk_fp8_f32(v, 0.0f, 0, false);
    return (unsigned char)(p & 0xff);
}
// fast sigmoid: v_exp_f32 + v_rcp_f32 (no IEEE div expansion; ~1ulp rcp err)
__device__ __forceinline__ float sigf(float x) {
    return __builtin_amdgcn_rcpf(1.0f + __builtin_amdgcn_exp2f(x * -1.44269504f));
}
// element (p) of an f32x4 pair-slot without dynamic vector indexing
__device__ __forceinline__ float sel2(f32x4 v, int p) {
    return p ? v[1] : v[0];   // rows {p, p+2} hold identical values; take p
}
// async global->LDS, 16B per lane (dest = wave-uniform base + lane*16)
__device__ __forceinline__ void gload_lds16(const void* g, void* l) {
    __builtin_amdgcn_global_load_lds(
        (const __attribute__((address_space(1))) void*)g,
        (__attribute__((address_space(3))) void*)l, 16, 0, 0);
}
// assemble i32x8 fragment from two 16B LDS chunks (compile-time indices only)
__device__ __forceinline__ i32x8 mk8(u32x4 lo, u32x4 hi) {
    i32x8 r;
    r[0] = (int)lo[0]; r[1] = (int)lo[1]; r[2] = (int)lo[2]; r[3] = (int)lo[3];
    r[4] = (int)hi[0]; r[5] = (int)hi[1]; r[6] = (int)hi[2]; r[7] = (int)hi[3];
    return r;
}

// ---------------- K0: merged prep (gather | Wx transpose | Wd transpose) ----
// Region 0: 32768 blocks -> embedding gather -> fp8, K-padded to 384
// Region 1:  2048 blocks -> Wx (f|b) transposed fp8 [2048][384]
// Region 2:    86 blocks -> Wd transposed bf16 [64][512], flat-indexed
// (prep_wh8 canNOT merge here: WhP8 aliases X8's region, written after K1.)
__global__ void k_prep_all(const int* __restrict__ tokens, const float* __restrict__ emb,
                           const float* __restrict__ Wx_f, const float* __restrict__ Wx_b,
                           const float* __restrict__ Wd,
                           unsigned char* __restrict__ X8,
                           unsigned char* __restrict__ W8T,
                           unsigned short* __restrict__ WdT16) {
    int blk = blockIdx.x, k = threadIdx.x;           // k: 0..383
    if (blk < NROWS) {                               // gather: r = s*128 + b
        int b = blk & 127, s = blk >> 7;
        int tok = tokens[b * S_ + s];
        float v = (k < EMB_) ? emb[(long)tok * EMB_ + k] : 0.0f;
        X8[(long)blk * KP8 + k] = f2fp8(v);
    } else if (blk < NROWS + NCOLS) {                // Wx transpose -> fp8
        int c = blk - NROWS;
        float v = 0.0f;
        if (k < EMB_) v = (c < GF) ? Wx_f[k * GF + c] : Wx_b[k * GF + (c - GF)];
        W8T[(long)c * KP8 + k] = f2fp8(v);
    } else {                                         // Wd transpose, flat
        int e = (blk - NROWS - NCOLS) * 384 + k;     // valid < 32768
        if (e < 64 * 512) {
            int c = e >> 9, kk = e & 511;
            float v = (c < TAGS_) ? Wd[kk * TAGS_ + c] : 0.0f;
            WdT16[c * 512 + kk] = f2bf(v);
        }
    }
}

// ---------------- K0e: Wh ALL 4 gates -> fp8 e4m3 [2 dir][4 g][256 j][256 k]-
// Runs after K1 (WhP8 aliases the then-dead X8 region).
__global__ void k_prep_wh8(const float* __restrict__ Wh_f, const float* __restrict__ Wh_b,
                           unsigned char* __restrict__ WhP8) {
    int row = blockIdx.x;          // 0..2047 = (d*4+gi)*256 + j
    int k = threadIdx.x;           // 0..255
    int d = row >> 10, rr = row & 1023, gi = rr >> 8, j = rr & 255;
    const float* Wh = d ? Wh_b : Wh_f;
    WhP8[(long)row * 256 + k] = f2fp8(Wh[k * GF + gi * HID_ + j]);
}

// ---------------- K1: xz = X @ Wx + b  (fp8 MX-scaled MFMA, LDS-staged) -----
// Round-9: inputs fp8 e4m3, mfma_scale_f32_16x16x128_f8f6f4 (scale=1.0) —
// same instruction + fragment layout verified in k_recurrence. vs bf16 r6:
// staged bytes/block 160->96 KB, MFMA issue 3100->1656 cyc, K-steps 5->3.
// Staging keeps r6's geometry (128-B rows = 8 x 16-B chunks, XOR j^(row&7)
// on the GLOBAL SOURCE, linear gload_lds dest). The 32-B fragment is read as
// its two logical 16-B chunks (2q, 2q+1) at their individually-swizzled LDS
// addresses and assembled in-register (i32x8 = 2 x ds_read_b128 either way),
// preserving A/B k-alignment; each b128 keeps the 2-lanes/bank free pattern.
__global__ __launch_bounds__(256) void k_gemm_xz(
    const unsigned char* __restrict__ X8, const unsigned char* __restrict__ W8T,
    const float* __restrict__ b_f, const float* __restrict__ b_b,
    unsigned long long* __restrict__ xzP) {
    __shared__ __align__(16) unsigned char A8s[2][128 * 128];  // 2 x 16 KB
    __shared__ __align__(16) unsigned char B8s[2][128 * 128];  // 2 x 16 KB
    int w = threadIdx.x >> 6, lane = threadIdx.x & 63;
    int quad = lane >> 4, l16 = lane & 15;
    int m0 = blockIdx.x * 128;
    int n0 = blockIdx.y * 128;

    int rlane = lane >> 3;                 // 0..7 row within 8-row group
    int jpos  = lane & 7;                  // 16B-chunk position in LDS row
    int jsrc  = jpos ^ (rlane & 7);        // pre-swizzled source chunk

    f32x4 acc[2][8];
#pragma unroll
    for (int mt = 0; mt < 2; ++mt)
#pragma unroll
        for (int nt = 0; nt < 8; ++nt) acc[mt][nt] = (f32x4){0.f, 0.f, 0.f, 0.f};

#define STAGE(ST, BUFI) do {                                                    \
    int k0_ = (ST) * 128;                                                       \
    _Pragma("unroll")                                                           \
    for (int i_ = 0; i_ < 4; ++i_) {                                            \
        int rb_ = (w * 4 + i_) * 8;                                             \
        int r_  = rb_ + rlane;                                                  \
        gload_lds16(X8 + (long)(m0 + r_) * KP8 + k0_ + jsrc * 16,               \
                    &A8s[BUFI][rb_ * 128]);                                     \
    }                                                                           \
    _Pragma("unroll")                                                           \
    for (int i_ = 0; i_ < 4; ++i_) {                                            \
        int rb_ = (w * 4 + i_) * 8;                                             \
        int r_  = rb_ + rlane;                                                  \
        gload_lds16(W8T + (long)(n0 + r_) * KP8 + k0_ + jsrc * 16,              \
                    &B8s[BUFI][rb_ * 128]);                                     \
    }                                                                           \
} while (0)

    STAGE(0, 0);
    __syncthreads();
#pragma unroll
    for (int st = 0; st < 3; ++st) {       // 3 x K=128 = KP8 384
        if (st < 2) STAGE(st + 1, (st + 1) & 1);
        int bufi = st & 1;
        i32x8 a[2], bb[8];
#pragma unroll
        for (int mt = 0; mt < 2; ++mt) {
            int mrow = w * 32 + mt * 16 + l16;
            int x_ = mrow & 7;
            u32x4 lo = *reinterpret_cast<const u32x4*>(
                &A8s[bufi][mrow * 128 + ((2 * quad) ^ x_) * 16]);
            u32x4 hi = *reinterpret_cast<const u32x4*>(
                &A8s[bufi][mrow * 128 + ((2 * quad + 1) ^ x_) * 16]);
            a[mt] = mk8(lo, hi);
        }
#pragma unroll
        for (int nt = 0; nt < 8; ++nt) {
            int nrow = nt * 16 + l16;
            int x_ = nrow & 7;
            u32x4 lo = *reinterpret_cast<const u32x4*>(
                &B8s[bufi][nrow * 128 + ((2 * quad) ^ x_) * 16]);
            u32x4 hi = *reinterpret_cast<const u32x4*>(
                &B8s[bufi][nrow * 128 + ((2 * quad + 1) ^ x_) * 16]);
            bb[nt] = mk8(lo, hi);
        }
#pragma unroll
        for (int mt = 0; mt < 2; ++mt)
#pragma unroll
            for (int nt = 0; nt < 8; ++nt)
#if __has_builtin(__builtin_amdgcn_mfma_scale_f32_16x16x128_f8f6f4)
                acc[mt][nt] = __builtin_amdgcn_mfma_scale_f32_16x16x128_f8f6f4(
                    a[mt], bb[nt], acc[mt][nt], 0, 0, 0, 0x7F, 0, 0x7F);
#else
                acc[mt][nt] = acc[mt][nt];  // unreachable on gfx950
#endif
        __syncthreads();
    }
#undef STAGE

    int s = blockIdx.x;            // m>>7
#pragma unroll
    for (int mt = 0; mt < 2; ++mt) {
        int grp = w * 2 + mt;      // (b>>4)
#pragma unroll
        for (int nt = 0; nt < 8; ++nt) {
            int col = n0 + nt * 16 + l16;
            int dir = col >> 10, cc = col & 1023;
            int gate = cc >> 8, u16 = (cc & 255) >> 4;
            float bias = dir ? b_b[cc] : b_f[cc];
            unsigned long long pk = 0;
#pragma unroll
            for (int r = 0; r < 4; ++r)
                pk |= (unsigned long long)f2bf(acc[mt][nt][r] + bias) << (16 * r);
            long idx8 = ((long)(s * 16 + dir * 8 + grp)) * 4096 +
                        (gate * 16 + u16) * 64 + quad * 16 + l16;
            xzP[idx8] = pk;
        }
    }
}

// ---------------- K2: bidirectional LSTM recurrence, single-CU chains -------
// r3 structure + all-fp8 gates (verified r7/r8: 212-213us, absmax unchanged).
// step ~1990 cyc = 1104 MFMA-issue + ~750 VALU + ~220 stall. CONTROL: byte-
// identical to r8.
__global__ __launch_bounds__(512, 2) void k_recurrence(
    const unsigned char* __restrict__ WhP8,
    const unsigned long long* __restrict__ xzP, unsigned short* __restrict__ hcat16) {
    __shared__ __align__(16) unsigned char lds[1152];  // h8: 2 buf x 2 par x 288 B
    int tid = threadIdx.x;
    int w = tid >> 6, lane = tid & 63, quad = lane >> 4, l16 = lane & 15;
    int blk = blockIdx.x;
    int d = blk >> 6, bg2 = blk & 63;           // batch pair b0 = bg2*2
    int p = quad & 1;                            // lane's batch parity
    int cg = quad >> 1;                          // lane's colgroup (0/1)
    int col = 16 * (2 * w + cg) + l16;           // lane's cell column
    int rp = l16 & 1;                            // A-row parity of this lane's row

    // all-gate fp8 K=128 scaled-MFMA B fragments, register-pinned (128 VGPR)
    i32x8 wh8s[4][2][2];
#pragma unroll
    for (int gi = 0; gi < 4; ++gi)
#pragma unroll
        for (int cgi = 0; cgi < 2; ++cgi)
#pragma unroll
            for (int kt2 = 0; kt2 < 2; ++kt2) {
                const unsigned char* wp8 = WhP8 +
                    ((long)((d * 4 + gi) * 256 + 16 * (2 * w + cgi) + l16)) * 256 +
                    kt2 * 128 + quad * 32;
                i32x8 v = *reinterpret_cast<const i32x8*>(wp8);
                asm volatile("" : "+v"(v));
                wh8s[gi][cgi][kt2] = v;
            }

    float c2 = 0.f;

    // xz addressing: u16 index = (s*16 + rowc)*16384 + ga*4096 + laneoff
    const unsigned short* xzU = (const unsigned short*)xzP;
    int rowc = d * 8 + (bg2 >> 3);
    unsigned int laneoff = (unsigned)((2 * w + cg) * 256 +
                                      (((bg2 >> 1) & 3) * 16 + l16) * 4 +
                                      2 * (bg2 & 1) + p);

    // preload xz for first step (4 ushorts per lane: gates i,f,g,o)
    unsigned short xzu[4];
    {
        int s0 = d ? 255 : 0;
        const unsigned short* ps = xzU + (unsigned long)(s0 * 16 + rowc) * 16384;
#pragma unroll
        for (int ga = 0; ga < 4; ++ga) xzu[ga] = ps[laneoff + ga * 4096];
    }

    for (int t = 0; t < 256; ++t) {
        int s = d ? (255 - t) : t;
        int pb = t & 1, cb = pb ^ 1;
        f32x4 acc8[4][2];
#pragma unroll
        for (int gi = 0; gi < 4; ++gi)
#pragma unroll
            for (int cgi = 0; cgi < 2; ++cgi) acc8[gi][cgi] = (f32x4){0.f, 0.f, 0.f, 0.f};

        if (t > 0) {
#pragma unroll
            for (int kt2 = 0; kt2 < 2; ++kt2) {
                i32x8 A8 = *reinterpret_cast<const i32x8*>(
                    lds + cb * 576 + rp * 288 + kt2 * 128 + quad * 32);
#pragma unroll
                for (int cgi = 0; cgi < 2; ++cgi)
#pragma unroll
                    for (int gi = 0; gi < 4; ++gi)
#if __has_builtin(__builtin_amdgcn_mfma_scale_f32_16x16x128_f8f6f4)
                        acc8[gi][cgi] = __builtin_amdgcn_mfma_scale_f32_16x16x128_f8f6f4(
                            A8, wh8s[gi][cgi][kt2], acc8[gi][cgi], 0, 0, 0, 0x7F, 0, 0x7F);
#else
                        acc8[gi][cgi] = acc8[gi][cgi];  // unreachable on gfx950
#endif
            }
        }
        // extract current-step xz addends (bf16 -> f32 is one shl each)
        float xa0 = __uint_as_float((unsigned int)xzu[0] << 16);
        float xa1 = __uint_as_float((unsigned int)xzu[1] << 16);
        float xa2 = __uint_as_float((unsigned int)xzu[2] << 16);
        float xa3 = __uint_as_float((unsigned int)xzu[3] << 16);
        // prefetch next step (fire-and-forget; consumed after next barrier)
        {
            int sn = d ? (s ? s - 1 : 0) : (s < 255 ? s + 1 : 255);
            const unsigned short* ps = xzU + (unsigned long)(sn * 16 + rowc) * 16384;
#pragma unroll
            for (int ga = 0; ga < 4; ++ga) xzu[ga] = ps[laneoff + ga * 4096];
        }
        // gates: lane's cell (batch bg2*2+p, col). C row m=quad*4+r has batch
        // m&1=r&1 -> element p (== element p+2). Colgroup pick by cg.
        float zi = (cg ? sel2(acc8[0][1], p) : sel2(acc8[0][0], p)) + xa0;
        float zf = (cg ? sel2(acc8[1][1], p) : sel2(acc8[1][0], p)) + xa1;
        float zg = (cg ? sel2(acc8[2][1], p) : sel2(acc8[2][0], p)) + xa2;
        float zo = (cg ? sel2(acc8[3][1], p) : sel2(acc8[3][0], p)) + xa3;
        float c = sigf(zf) * c2 + sigf(zi) * fmaxf(zg, 0.0f);
        c2 = c;
        float h = sigf(zo) * fmaxf(c, 0.0f);

        int p8 = __builtin_amdgcn_cvt_pk_fp8_f32(h, h, 0, false);
        *(lds + pb * 576 + p * 288 + col) = (unsigned char)(p8 & 0xff);
        // hcat direct from register (fire-and-forget; barrier won't drain it)
        hcat16[((long)(bg2 * 2 + p) * S_ + s) * 512 + d * HID_ + col] = f2bf(h);
        // LDS-only barrier: no vmcnt drain (global stores/loads stay in flight)
        asm volatile("s_waitcnt lgkmcnt(0)\n\ts_barrier" ::: "memory");
    }
}

// ---------------- K3: logits = hcat @ Wd, +bd, fused softmax -> out ---------
// LDS-staged (r8, verified). A [128][64] bf16 chunks, XOR-swizzle on global
// source, ds_read_b128 with matching XOR. Fused softmax epilogue.
__global__ __launch_bounds__(256) void k_gemm_logits(
    const unsigned short* __restrict__ hcat16, const unsigned short* __restrict__ WdT16,
    const float* __restrict__ bd, float* __restrict__ out) {
    __shared__ __align__(16) unsigned short Asw[2][128 * 64];  // 2 x 16 KB
    __shared__ __align__(16) unsigned short Bsw[2][64 * 64];   // 2 x 8 KB
    int w = threadIdx.x >> 6, lane = threadIdx.x & 63;
    int quad = lane >> 4, l16 = lane & 15;
    int m0 = blockIdx.x * 128;
    int rlane = lane >> 3, jpos = lane & 7;
    int jsrc = jpos ^ (rlane & 7);

    f32x4 acc[2][4];
#pragma unroll
    for (int mt = 0; mt < 2; ++mt)
#pragma unroll
        for (int nt = 0; nt < 4; ++nt) acc[mt][nt] = (f32x4){0.f, 0.f, 0.f, 0.f};

#define STAGE3(ST, BUFI) do {                                                   \
    int k0_ = (ST) * 64;                                                        \
    _Pragma("unroll")                                                           \
    for (int i_ = 0; i_ < 4; ++i_) {                                            \
        int rb_ = (w * 4 + i_) * 8;                                             \
        int r_  = rb_ + rlane;                                                  \
        gload_lds16(hcat16 + (long)(m0 + r_) * 512 + k0_ + jsrc * 8,            \
                    &Asw[BUFI][rb_ * 64]);                                      \
    }                                                                           \
    _Pragma("unroll")                                                           \
    for (int i_ = 0; i_ < 2; ++i_) {                                            \
        int rb_ = (w * 2 + i_) * 8;                                             \
        int r_  = rb_ + rlane;                                                  \
        gload_lds16(WdT16 + (long)r_ * 512 + k0_ + jsrc * 8,                    \
                    &Bsw[BUFI][rb_ * 64]);                                      \
    }                                                                           \
} while (0)

    STAGE3(0, 0);
    __syncthreads();
#pragma unroll
    for (int st = 0; st < 8; ++st) {       // 8 x BK=64 = K 512
        if (st < 7) STAGE3(st + 1, (st + 1) & 1);
        int bufi = st & 1;
#pragma unroll
        for (int ks = 0; ks < 2; ++ks) {
            bf16x8 a[2], bb[4];
#pragma unroll
            for (int mt = 0; mt < 2; ++mt) {
                int mrow = w * 32 + mt * 16 + l16;
                int jp = (ks * 4 + quad) ^ (l16 & 7);
                a[mt] = ldb8(&Asw[bufi][mrow * 64 + jp * 8]);
            }
#pragma unroll
            for (int nt = 0; nt < 4; ++nt) {
                int nrow = nt * 16 + l16;
                int jp = (ks * 4 + quad) ^ (l16 & 7);
                bb[nt] = ldb8(&Bsw[bufi][nrow * 64 + jp * 8]);
            }
#pragma unroll
            for (int mt = 0; mt < 2; ++mt)
#pragma unroll
                for (int nt = 0; nt < 4; ++nt)
                    acc[mt][nt] = __builtin_amdgcn_mfma_f32_16x16x32_bf16(a[mt], bb[nt], acc[mt][nt], 0, 0, 0);
        }
        __syncthreads();
    }
#undef STAGE3

#pragma unroll
    for (int mt = 0; mt < 2; ++mt) {
#pragma unroll
        for (int r = 0; r < 4; ++r) {
            int row = m0 + w * 32 + mt * 16 + quad * 4 + r;
            float vv[4];
            float mx = -3.0e38f;
#pragma unroll
            for (int nt = 0; nt < 4; ++nt) {
                int cl = nt * 16 + l16;
                float tv = (cl < TAGS_) ? (acc[mt][nt][r] + bd[cl]) : -3.0e38f;
                vv[nt] = tv;
                mx = fmaxf(mx, tv);
            }
#pragma unroll
            for (int off = 8; off >= 1; off >>= 1) mx = fmaxf(mx, __shfl_xor(mx, off, 64));
            float sum = 0.f;
#pragma unroll
            for (int nt = 0; nt < 4; ++nt) {
                int cl = nt * 16 + l16;
                float e = (cl < TAGS_) ? __expf(vv[nt] - mx) : 0.0f;
                vv[nt] = e;
                sum += e;
            }
#pragma unroll
            for (int off = 8; off >= 1; off >>= 1) sum += __shfl_xor(sum, off, 64);
            float rs = __builtin_amdgcn_rcpf(sum);
#pragma unroll
            for (int nt = 0; nt < 4; ++nt) {
                int cl = nt * 16 + l16;
                if (cl < TAGS_) out[(long)row * TAGS_ + cl] = vv[nt] * rs;
            }
        }
    }
}

extern "C" void kernel_launch(void* const* d_in, const int* in_sizes, int n_in,
                              void* d_out, int out_size, void* d_ws, size_t ws_size,
                              hipStream_t stream) {
    (void)in_sizes; (void)n_in; (void)out_size; (void)ws_size;
    const int*   tokens = (const int*)  d_in[0];
    const float* emb    = (const float*)d_in[1];
    const float* Wx_f   = (const float*)d_in[2];
    const float* Wh_f   = (const float*)d_in[3];
    const float* b_f    = (const float*)d_in[4];
    const float* Wx_b   = (const float*)d_in[5];
    const float* Wh_b   = (const float*)d_in[6];
    const float* b_b    = (const float*)d_in[7];
    const float* Wd     = (const float*)d_in[8];
    const float* bd     = (const float*)d_in[9];
    float* out = (float*)d_out;

    // workspace layout (bytes): total 190,119,936
    uint8_t* w = (uint8_t*)d_ws;
    unsigned char*  X8     = (unsigned char*)(w);                   // 12,582,912 (dead after K1)
    unsigned char*  W8T    = (unsigned char*)(w + 12582912);        //    786,432 (dead after K1)
    // alias inside X8's region, used only after K1:
    unsigned char*  WhP8   = (unsigned char*)(w);                   //    524,288
    unsigned short* WdT16  = (unsigned short*)(w + 22282240);       //     65,536
    unsigned long long* xzP = (unsigned long long*)(w + 22347776);  // 134,217,728
    unsigned short* hcat16 = (unsigned short*)(w + 156565504);      //  33,554,432

    // merged prep: gather (32768) | Wx-T (2048) | Wd-T (86 flat blocks)
    k_prep_all  <<<dim3(NROWS + NCOLS + 86), dim3(KP8), 0, stream>>>(
        tokens, emb, Wx_f, Wx_b, Wd, X8, W8T, WdT16);
    k_gemm_xz   <<<dim3(256, 16),   dim3(256),  0, stream>>>(X8, W8T, b_f, b_b, xzP);
    // X8 region now dead -> build WhP8 in it (all 4 gates, fp8)
    k_prep_wh8  <<<dim3(2048),      dim3(256),  0, stream>>>(Wh_f, Wh_b, WhP8);
    k_recurrence<<<dim3(128),       dim3(512),  0, stream>>>(WhP8, xzP, hcat16);
    k_gemm_logits<<<dim3(256),      dim3(256),  0, stream>>>(hcat16, WdT16, bd, out);
}

// Round 10
// 382.911 us; speedup vs baseline: 1.8042x; 1.0491x over previous
//
#include <hip/hip_runtime.h>
#include <stdint.h>

#define B_    128
#define S_    256
#define EMB_  300
#define HID_  256
#define TAGS_ 50
#define KP8   384           // EMB padded to multiple of 128 (fp8 K1 path)
#define NROWS (B_ * S_)     // 32768, row r = s*128 + b
#define GF    (4 * HID_)    // 1024 gate cols per direction
#define NCOLS (2 * GF)      // 2048 (fwd | bwd)

typedef __bf16 bf16x8 __attribute__((ext_vector_type(8)));
typedef float  f32x4  __attribute__((ext_vector_type(4)));
typedef unsigned int u32x4 __attribute__((ext_vector_type(4)));
typedef int    i32x8  __attribute__((ext_vector_type(8)));

__device__ __forceinline__ unsigned short f2bf(float f) {
    unsigned int u = __float_as_uint(f);
    unsigned int r = (u + 0x7fffu + ((u >> 16) & 1u)) >> 16;  // RNE
    return (unsigned short)r;
}
__device__ __forceinline__ bf16x8 ldb8(const unsigned short* p) {
    u32x4 v = *reinterpret_cast<const u32x4*>(p);
    return __builtin_bit_cast(bf16x8, v);
}
__device__ __forceinline__ unsigned char f2fp8(float v) {
    int p = __builtin_amdgcn_cvt_pk_fp8_f32(v, 0.0f, 0, false);
    return (unsigned char)(p & 0xff);
}
// fp8 e4m3 -> f32 (builtin preferred; arithmetic fallback is exact)
__device__ __forceinline__ float fp8_to_f32(unsigned int b) {
#if __has_builtin(__builtin_amdgcn_cvt_f32_fp8)
    return __builtin_amdgcn_cvt_f32_fp8((int)b, 0);
#else
    unsigned int s = (b >> 7) & 1u, e = (b >> 3) & 15u, m = b & 7u;
    float mag = e ? __uint_as_float(((e + 120u) << 23) | (m << 20))
                  : (float)m * 0.001953125f;   // subnormal: m * 2^-9
    return s ? -mag : mag;
#endif
}
// fast sigmoid: v_exp_f32 + v_rcp_f32 (no IEEE div expansion; ~1ulp rcp err)
__device__ __forceinline__ float sigf(float x) {
    return __builtin_amdgcn_rcpf(1.0f + __builtin_amdgcn_exp2f(x * -1.44269504f));
}
// element (p) of an f32x4 pair-slot without dynamic vector indexing
__device__ __forceinline__ float sel2(f32x4 v, int p) {
    return p ? v[1] : v[0];   // rows {p, p+2} hold identical values; take p
}
// async global->LDS, 16B per lane (dest = wave-uniform base + lane*16)
__device__ __forceinline__ void gload_lds16(const void* g, void* l) {
    __builtin_amdgcn_global_load_lds(
        (const __attribute__((address_space(1))) void*)g,
        (__attribute__((address_space(3))) void*)l, 16, 0, 0);
}
// assemble i32x8 fragment from two 16B LDS chunks (compile-time indices only)
__device__ __forceinline__ i32x8 mk8(u32x4 lo, u32x4 hi) {
    i32x8 r;
    r[0] = (int)lo[0]; r[1] = (int)lo[1]; r[2] = (int)lo[2]; r[3] = (int)lo[3];
    r[4] = (int)hi[0]; r[5] = (int)hi[1]; r[6] = (int)hi[2]; r[7] = (int)hi[3];
    return r;
}

// ---------------- K0: merged prep (gather | Wx-T | Wd-T | Wh fp8) -----------
// Region 0: 32768 blocks -> embedding gather -> fp8, K-padded to 384
// Region 1:  2048 blocks -> Wx (f|b) transposed fp8 [2048][384]
// Region 2:    86 blocks -> Wd transposed bf16 [64][512], flat-indexed
// Region 3:  2048 blocks -> Wh ALL 4 gates fp8 [2 dir][4 g][256 j][256 k]
// (WhP8 no longer aliases X8 -> wh8 prep merges here, one launch fewer.)
__global__ void k_prep_all(const int* __restrict__ tokens, const float* __restrict__ emb,
                           const float* __restrict__ Wx_f, const float* __restrict__ Wx_b,
                           const float* __restrict__ Wd,
                           const float* __restrict__ Wh_f, const float* __restrict__ Wh_b,
                           unsigned char* __restrict__ X8,
                           unsigned char* __restrict__ W8T,
                           unsigned short* __restrict__ WdT16,
                           unsigned char* __restrict__ WhP8) {
    int blk = blockIdx.x, k = threadIdx.x;           // k: 0..383
    if (blk < NROWS) {                               // gather: r = s*128 + b
        int b = blk & 127, s = blk >> 7;
        int tok = tokens[b * S_ + s];
        float v = (k < EMB_) ? emb[(long)tok * EMB_ + k] : 0.0f;
        X8[(long)blk * KP8 + k] = f2fp8(v);
    } else if (blk < NROWS + NCOLS) {                // Wx transpose -> fp8
        int c = blk - NROWS;
        float v = 0.0f;
        if (k < EMB_) v = (c < GF) ? Wx_f[k * GF + c] : Wx_b[k * GF + (c - GF)];
        W8T[(long)c * KP8 + k] = f2fp8(v);
    } else if (blk < NROWS + NCOLS + 86) {           // Wd transpose, flat
        int e = (blk - NROWS - NCOLS) * 384 + k;     // valid < 32768
        if (e < 64 * 512) {
            int c = e >> 9, kk = e & 511;
            float v = (c < TAGS_) ? Wd[kk * TAGS_ + c] : 0.0f;
            WdT16[c * 512 + kk] = f2bf(v);
        }
    } else if (k < 256) {                            // Wh -> fp8 (all gates)
        int row = blk - (NROWS + NCOLS + 86);        // 0..2047 = (d*4+gi)*256+j
        int d = row >> 10, rr = row & 1023, gi = rr >> 8, j = rr & 255;
        const float* Wh = d ? Wh_b : Wh_f;
        WhP8[(long)row * 256 + k] = f2fp8(Wh[k * GF + gi * HID_ + j]);
    }
}

// ---------------- K1: xz = X @ Wx + b  (fp8 MX-scaled MFMA, LDS-staged) -----
// r9 structure (verified). Round-10 change: xzP stored as fp8 (u32 packs the
// 4 batches of a group; SAME idx8 formula in u32 units — the layout is the
// u64 one with bf16->fp8). r9 proved ~5% xz rel-err is invisible at the
// output (absmax pinned at 1.22e-4); fp8 storage adds 3.6% on top.
// HBM write 134 -> 67 MB. Epilogue packs 4 gates via 2 cvt_pk_fp8.
__global__ __launch_bounds__(256) void k_gemm_xz(
    const unsigned char* __restrict__ X8, const unsigned char* __restrict__ W8T,
    const float* __restrict__ b_f, const float* __restrict__ b_b,
    unsigned int* __restrict__ xz32) {
    __shared__ __align__(16) unsigned char A8s[2][128 * 128];  // 2 x 16 KB
    __shared__ __align__(16) unsigned char B8s[2][128 * 128];  // 2 x 16 KB
    int w = threadIdx.x >> 6, lane = threadIdx.x & 63;
    int quad = lane >> 4, l16 = lane & 15;
    int m0 = blockIdx.x * 128;
    int n0 = blockIdx.y * 128;

    int rlane = lane >> 3;                 // 0..7 row within 8-row group
    int jpos  = lane & 7;                  // 16B-chunk position in LDS row
    int jsrc  = jpos ^ (rlane & 7);        // pre-swizzled source chunk

    f32x4 acc[2][8];
#pragma unroll
    for (int mt = 0; mt < 2; ++mt)
#pragma unroll
        for (int nt = 0; nt < 8; ++nt) acc[mt][nt] = (f32x4){0.f, 0.f, 0.f, 0.f};

#define STAGE(ST, BUFI) do {                                                    \
    int k0_ = (ST) * 128;                                                       \
    _Pragma("unroll")                                                           \
    for (int i_ = 0; i_ < 4; ++i_) {                                            \
        int rb_ = (w * 4 + i_) * 8;                                             \
        int r_  = rb_ + rlane;                                                  \
        gload_lds16(X8 + (long)(m0 + r_) * KP8 + k0_ + jsrc * 16,               \
                    &A8s[BUFI][rb_ * 128]);                                     \
    }                                                                           \
    _Pragma("unroll")                                                           \
    for (int i_ = 0; i_ < 4; ++i_) {                                            \
        int rb_ = (w * 4 + i_) * 8;                                             \
        int r_  = rb_ + rlane;                                                  \
        gload_lds16(W8T + (long)(n0 + r_) * KP8 + k0_ + jsrc * 16,              \
                    &B8s[BUFI][rb_ * 128]);                                     \
    }                                                                           \
} while (0)

    STAGE(0, 0);
    __syncthreads();
#pragma unroll
    for (int st = 0; st < 3; ++st) {       // 3 x K=128 = KP8 384
        if (st < 2) STAGE(st + 1, (st + 1) & 1);
        int bufi = st & 1;
        i32x8 a[2], bb[8];
#pragma unroll
        for (int mt = 0; mt < 2; ++mt) {
            int mrow = w * 32 + mt * 16 + l16;
            int x_ = mrow & 7;
            u32x4 lo = *reinterpret_cast<const u32x4*>(
                &A8s[bufi][mrow * 128 + ((2 * quad) ^ x_) * 16]);
            u32x4 hi = *reinterpret_cast<const u32x4*>(
                &A8s[bufi][mrow * 128 + ((2 * quad + 1) ^ x_) * 16]);
            a[mt] = mk8(lo, hi);
        }
#pragma unroll
        for (int nt = 0; nt < 8; ++nt) {
            int nrow = nt * 16 + l16;
            int x_ = nrow & 7;
            u32x4 lo = *reinterpret_cast<const u32x4*>(
                &B8s[bufi][nrow * 128 + ((2 * quad) ^ x_) * 16]);
            u32x4 hi = *reinterpret_cast<const u32x4*>(
                &B8s[bufi][nrow * 128 + ((2 * quad + 1) ^ x_) * 16]);
            bb[nt] = mk8(lo, hi);
        }
#pragma unroll
        for (int mt = 0; mt < 2; ++mt)
#pragma unroll
            for (int nt = 0; nt < 8; ++nt)
#if __has_builtin(__builtin_amdgcn_mfma_scale_f32_16x16x128_f8f6f4)
                acc[mt][nt] = __builtin_amdgcn_mfma_scale_f32_16x16x128_f8f6f4(
                    a[mt], bb[nt], acc[mt][nt], 0, 0, 0, 0x7F, 0, 0x7F);
#else
                acc[mt][nt] = acc[mt][nt];  // unreachable on gfx950
#endif
        __syncthreads();
    }
#undef STAGE

    int s = blockIdx.x;            // m>>7
#pragma unroll
    for (int mt = 0; mt < 2; ++mt) {
        int grp = w * 2 + mt;      // (b>>4)
#pragma unroll
        for (int nt = 0; nt < 8; ++nt) {
            int col = n0 + nt * 16 + l16;
            int dir = col >> 10, cc = col & 1023;
            int gate = cc >> 8, u16 = (cc & 255) >> 4;
            float bias = dir ? b_b[cc] : b_f[cc];
            // bytes 0..3 = batches r=0..3 (b = grp*16 + quad*4 + r)
            int t0 = __builtin_amdgcn_cvt_pk_fp8_f32(
                acc[mt][nt][0] + bias, acc[mt][nt][1] + bias, 0, false);
            int t1 = __builtin_amdgcn_cvt_pk_fp8_f32(
                acc[mt][nt][2] + bias, acc[mt][nt][3] + bias, t0, true);
            long idx8 = ((long)(s * 16 + dir * 8 + grp)) * 4096 +
                        (gate * 16 + u16) * 64 + quad * 16 + l16;
            xz32[idx8] = (unsigned int)t1;
        }
    }
}

// ---------------- K2: bidirectional LSTM recurrence, single-CU chains -------
// r3 structure + all-fp8 gates (verified r7-r9: 212-214us). Round-10 diff is
// ONLY the xz load path: byte loads from the fp8 xz planes (byte-laneoff is
// numerically identical to the old u16-laneoff; plane stride 4096 B, s-super-
// row stride 16384 B) and cvt_f32_fp8 extraction (1 op, same as the old shl).
// Everything else byte-identical. step ~1990 cyc = 1104 MFMA + ~750 VALU.
__global__ __launch_bounds__(512, 2) void k_recurrence(
    const unsigned char* __restrict__ WhP8,
    const unsigned char* __restrict__ xz8, unsigned short* __restrict__ hcat16) {
    __shared__ __align__(16) unsigned char lds[1152];  // h8: 2 buf x 2 par x 288 B
    int tid = threadIdx.x;
    int w = tid >> 6, lane = tid & 63, quad = lane >> 4, l16 = lane & 15;
    int blk = blockIdx.x;
    int d = blk >> 6, bg2 = blk & 63;           // batch pair b0 = bg2*2
    int p = quad & 1;                            // lane's batch parity
    int cg = quad >> 1;                          // lane's colgroup (0/1)
    int col = 16 * (2 * w + cg) + l16;           // lane's cell column
    int rp = l16 & 1;                            // A-row parity of this lane's row

    // all-gate fp8 K=128 scaled-MFMA B fragments, register-pinned (128 VGPR)
    i32x8 wh8s[4][2][2];
#pragma unroll
    for (int gi = 0; gi < 4; ++gi)
#pragma unroll
        for (int cgi = 0; cgi < 2; ++cgi)
#pragma unroll
            for (int kt2 = 0; kt2 < 2; ++kt2) {
                const unsigned char* wp8 = WhP8 +
                    ((long)((d * 4 + gi) * 256 + 16 * (2 * w + cgi) + l16)) * 256 +
                    kt2 * 128 + quad * 32;
                i32x8 v = *reinterpret_cast<const i32x8*>(wp8);
                asm volatile("" : "+v"(v));
                wh8s[gi][cgi][kt2] = v;
            }

    float c2 = 0.f;

    // xz addressing (fp8): byte = (s*16+rowc)*16384 + ga*4096 + laneoff
    int rowc = d * 8 + (bg2 >> 3);
    unsigned int laneoff = (unsigned)((2 * w + cg) * 256 +
                                      (((bg2 >> 1) & 3) * 16 + l16) * 4 +
                                      2 * (bg2 & 1) + p);

    // preload xz for first step (4 bytes per lane: gates i,f,g,o)
    unsigned int xzu[4];
    {
        int s0 = d ? 255 : 0;
        const unsigned char* ps = xz8 + (unsigned long)(s0 * 16 + rowc) * 16384 + laneoff;
#pragma unroll
        for (int ga = 0; ga < 4; ++ga) xzu[ga] = ps[ga * 4096];
    }

    for (int t = 0; t < 256; ++t) {
        int s = d ? (255 - t) : t;
        int pb = t & 1, cb = pb ^ 1;
        f32x4 acc8[4][2];
#pragma unroll
        for (int gi = 0; gi < 4; ++gi)
#pragma unroll
            for (int cgi = 0; cgi < 2; ++cgi) acc8[gi][cgi] = (f32x4){0.f, 0.f, 0.f, 0.f};

        if (t > 0) {
#pragma unroll
            for (int kt2 = 0; kt2 < 2; ++kt2) {
                i32x8 A8 = *reinterpret_cast<const i32x8*>(
                    lds + cb * 576 + rp * 288 + kt2 * 128 + quad * 32);
#pragma unroll
                for (int cgi = 0; cgi < 2; ++cgi)
#pragma unroll
                    for (int gi = 0; gi < 4; ++gi)
#if __has_builtin(__builtin_amdgcn_mfma_scale_f32_16x16x128_f8f6f4)
                        acc8[gi][cgi] = __builtin_amdgcn_mfma_scale_f32_16x16x128_f8f6f4(
                            A8, wh8s[gi][cgi][kt2], acc8[gi][cgi], 0, 0, 0, 0x7F, 0, 0x7F);
#else
                        acc8[gi][cgi] = acc8[gi][cgi];  // unreachable on gfx950
#endif
            }
        }
        // extract current-step xz addends (fp8 -> f32, one cvt each)
        float xa0 = fp8_to_f32(xzu[0]);
        float xa1 = fp8_to_f32(xzu[1]);
        float xa2 = fp8_to_f32(xzu[2]);
        float xa3 = fp8_to_f32(xzu[3]);
        // prefetch next step (fire-and-forget; consumed after next barrier)
        {
            int sn = d ? (s ? s - 1 : 0) : (s < 255 ? s + 1 : 255);
            const unsigned char* ps = xz8 + (unsigned long)(sn * 16 + rowc) * 16384 + laneoff;
#pragma unroll
            for (int ga = 0; ga < 4; ++ga) xzu[ga] = ps[ga * 4096];
        }
        // gates: lane's cell (batch bg2*2+p, col). C row m=quad*4+r has batch
        // m&1=r&1 -> element p (== element p+2). Colgroup pick by cg.
        float zi = (cg ? sel2(acc8[0][1], p) : sel2(acc8[0][0], p)) + xa0;
        float zf = (cg ? sel2(acc8[1][1], p) : sel2(acc8[1][0], p)) + xa1;
        float zg = (cg ? sel2(acc8[2][1], p) : sel2(acc8[2][0], p)) + xa2;
        float zo = (cg ? sel2(acc8[3][1], p) : sel2(acc8[3][0], p)) + xa3;
        float c = sigf(zf) * c2 + sigf(zi) * fmaxf(zg, 0.0f);
        c2 = c;
        float h = sigf(zo) * fmaxf(c, 0.0f);

        int p8 = __builtin_amdgcn_cvt_pk_fp8_f32(h, h, 0, false);
        *(lds + pb * 576 + p * 288 + col) = (unsigned char)(p8 & 0xff);
        // hcat direct from register (fire-and-forget; barrier won't drain it)
        hcat16[((long)(bg2 * 2 + p) * S_ + s) * 512 + d * HID_ + col] = f2bf(h);
        // LDS-only barrier: no vmcnt drain (global stores/loads stay in flight)
        asm volatile("s_waitcnt lgkmcnt(0)\n\ts_barrier" ::: "memory");
    }
}

// ---------------- K3: logits = hcat @ Wd, +bd, fused softmax -> out ---------
// LDS-staged (r8, verified). A [128][64] bf16 chunks, XOR-swizzle on global
// source, ds_read_b128 with matching XOR. Fused softmax epilogue. Unchanged.
__global__ __launch_bounds__(256) void k_gemm_logits(
    const unsigned short* __restrict__ hcat16, const unsigned short* __restrict__ WdT16,
    const float* __restrict__ bd, float* __restrict__ out) {
    __shared__ __align__(16) unsigned short Asw[2][128 * 64];  // 2 x 16 KB
    __shared__ __align__(16) unsigned short Bsw[2][64 * 64];   // 2 x 8 KB
    int w = threadIdx.x >> 6, lane = threadIdx.x & 63;
    int quad = lane >> 4, l16 = lane & 15;
    int m0 = blockIdx.x * 128;
    int rlane = lane >> 3, jpos = lane & 7;
    int jsrc = jpos ^ (rlane & 7);

    f32x4 acc[2][4];
#pragma unroll
    for (int mt = 0; mt < 2; ++mt)
#pragma unroll
        for (int nt = 0; nt < 4; ++nt) acc[mt][nt] = (f32x4){0.f, 0.f, 0.f, 0.f};

#define STAGE3(ST, BUFI) do {                                                   \
    int k0_ = (ST) * 64;                                                        \
    _Pragma("unroll")                                                           \
    for (int i_ = 0; i_ < 4; ++i_) {                                            \
        int rb_ = (w * 4 + i_) * 8;                                             \
        int r_  = rb_ + rlane;                                                  \
        gload_lds16(hcat16 + (long)(m0 + r_) * 512 + k0_ + jsrc * 8,            \
                    &Asw[BUFI][rb_ * 64]);                                      \
    }                                                                           \
    _Pragma("unroll")                                                           \
    for (int i_ = 0; i_ < 2; ++i_) {                                            \
        int rb_ = (w * 2 + i_) * 8;                                             \
        int r_  = rb_ + rlane;                                                  \
        gload_lds16(WdT16 + (long)r_ * 512 + k0_ + jsrc * 8,                    \
                    &Bsw[BUFI][rb_ * 64]);                                      \
    }                                                                           \
} while (0)

    STAGE3(0, 0);
    __syncthreads();
#pragma unroll
    for (int st = 0; st < 8; ++st) {       // 8 x BK=64 = K 512
        if (st < 7) STAGE3(st + 1, (st + 1) & 1);
        int bufi = st & 1;
#pragma unroll
        for (int ks = 0; ks < 2; ++ks) {
            bf16x8 a[2], bb[4];
#pragma unroll
            for (int mt = 0; mt < 2; ++mt) {
                int mrow = w * 32 + mt * 16 + l16;
                int jp = (ks * 4 + quad) ^ (l16 & 7);
                a[mt] = ldb8(&Asw[bufi][mrow * 64 + jp * 8]);
            }
#pragma unroll
            for (int nt = 0; nt < 4; ++nt) {
                int nrow = nt * 16 + l16;
                int jp = (ks * 4 + quad) ^ (l16 & 7);
                bb[nt] = ldb8(&Bsw[bufi][nrow * 64 + jp * 8]);
            }
#pragma unroll
            for (int mt = 0; mt < 2; ++mt)
#pragma unroll
                for (int nt = 0; nt < 4; ++nt)
                    acc[mt][nt] = __builtin_amdgcn_mfma_f32_16x16x32_bf16(a[mt], bb[nt], acc[mt][nt], 0, 0, 0);
        }
        __syncthreads();
    }
#undef STAGE3

#pragma unroll
    for (int mt = 0; mt < 2; ++mt) {
#pragma unroll
        for (int r = 0; r < 4; ++r) {
            int row = m0 + w * 32 + mt * 16 + quad * 4 + r;
            float vv[4];
            float mx = -3.0e38f;
#pragma unroll
            for (int nt = 0; nt < 4; ++nt) {
                int cl = nt * 16 + l16;
                float tv = (cl < TAGS_) ? (acc[mt][nt][r] + bd[cl]) : -3.0e38f;
                vv[nt] = tv;
                mx = fmaxf(mx, tv);
            }
#pragma unroll
            for (int off = 8; off >= 1; off >>= 1) mx = fmaxf(mx, __shfl_xor(mx, off, 64));
            float sum = 0.f;
#pragma unroll
            for (int nt = 0; nt < 4; ++nt) {
                int cl = nt * 16 + l16;
                float e = (cl < TAGS_) ? __expf(vv[nt] - mx) : 0.0f;
                vv[nt] = e;
                sum += e;
            }
#pragma unroll
            for (int off = 8; off >= 1; off >>= 1) sum += __shfl_xor(sum, off, 64);
            float rs = __builtin_amdgcn_rcpf(sum);
#pragma unroll
            for (int nt = 0; nt < 4; ++nt) {
                int cl = nt * 16 + l16;
                if (cl < TAGS_) out[(long)row * TAGS_ + cl] = vv[nt] * rs;
            }
        }
    }
}

extern "C" void kernel_launch(void* const* d_in, const int* in_sizes, int n_in,
                              void* d_out, int out_size, void* d_ws, size_t ws_size,
                              hipStream_t stream) {
    (void)in_sizes; (void)n_in; (void)out_size; (void)ws_size;
    const int*   tokens = (const int*)  d_in[0];
    const float* emb    = (const float*)d_in[1];
    const float* Wx_f   = (const float*)d_in[2];
    const float* Wh_f   = (const float*)d_in[3];
    const float* b_f    = (const float*)d_in[4];
    const float* Wx_b   = (const float*)d_in[5];
    const float* Wh_b   = (const float*)d_in[6];
    const float* b_b    = (const float*)d_in[7];
    const float* Wd     = (const float*)d_in[8];
    const float* bd     = (const float*)d_in[9];
    float* out = (float*)d_out;

    // workspace layout (bytes): total 190,119,936
    uint8_t* w = (uint8_t*)d_ws;
    unsigned char*  X8     = (unsigned char*)(w);                   // 12,582,912
    unsigned char*  W8T    = (unsigned char*)(w + 12582912);        //    786,432
    unsigned short* WdT16  = (unsigned short*)(w + 22282240);       //     65,536
    unsigned char*  xz8    = (unsigned char*)(w + 22347776);        // 67,108,864 (fp8)
    unsigned char*  WhP8   = (unsigned char*)(w + 89456640);        //    524,288 (no alias)
    unsigned short* hcat16 = (unsigned short*)(w + 156565504);      //  33,554,432

    // merged prep: gather (32768) | Wx-T (2048) | Wd-T (86) | Wh-fp8 (2048)
    k_prep_all  <<<dim3(NROWS + NCOLS + 86 + 2048), dim3(KP8), 0, stream>>>(
        tokens, emb, Wx_f, Wx_b, Wd, Wh_f, Wh_b, X8, W8T, WdT16, WhP8);
    k_gemm_xz   <<<dim3(256, 16),   dim3(256),  0, stream>>>(
        X8, W8T, b_f, b_b, (unsigned int*)xz8);
    k_recurrence<<<dim3(128),       dim3(512),  0, stream>>>(WhP8, xz8, hcat16);
    k_gemm_logits<<<dim3(256),      dim3(256),  0, stream>>>(hcat16, WdT16, bd, out);
}

// Round 11
// 371.745 us; speedup vs baseline: 1.8584x; 1.0300x over previous
//
#include <hip/hip_runtime.h>
#include <stdint.h>

#define B_    128
#define S_    256
#define EMB_  300
#define HID_  256
#define TAGS_ 50
#define KP8   384           // EMB padded to multiple of 128 (fp8 K1 path)
#define NROWS (B_ * S_)     // 32768, row r = s*128 + b
#define GF    (4 * HID_)    // 1024 gate cols per direction
#define NCOLS (2 * GF)      // 2048 (fwd | bwd)

typedef __bf16 bf16x8 __attribute__((ext_vector_type(8)));
typedef float  f32x4  __attribute__((ext_vector_type(4)));
typedef unsigned int u32x4 __attribute__((ext_vector_type(4)));
typedef int    i32x8  __attribute__((ext_vector_type(8)));

__device__ __forceinline__ unsigned short f2bf(float f) {
    unsigned int u = __float_as_uint(f);
    unsigned int r = (u + 0x7fffu + ((u >> 16) & 1u)) >> 16;  // RNE
    return (unsigned short)r;
}
__device__ __forceinline__ bf16x8 ldb8(const unsigned short* p) {
    u32x4 v = *reinterpret_cast<const u32x4*>(p);
    return __builtin_bit_cast(bf16x8, v);
}
__device__ __forceinline__ unsigned char f2fp8(float v) {
    int p = __builtin_amdgcn_cvt_pk_fp8_f32(v, 0.0f, 0, false);
    return (unsigned char)(p & 0xff);
}
// fp8 e4m3 -> f32 (builtin preferred; arithmetic fallback is exact)
__device__ __forceinline__ float fp8_to_f32(unsigned int b) {
#if __has_builtin(__builtin_amdgcn_cvt_f32_fp8)
    return __builtin_amdgcn_cvt_f32_fp8((int)b, 0);
#else
    unsigned int s = (b >> 7) & 1u, e = (b >> 3) & 15u, m = b & 7u;
    float mag = e ? __uint_as_float(((e + 120u) << 23) | (m << 20))
                  : (float)m * 0.001953125f;   // subnormal: m * 2^-9
    return s ? -mag : mag;
#endif
}
// fast sigmoid: v_exp_f32 + v_rcp_f32 (no IEEE div expansion; ~1ulp rcp err)
__device__ __forceinline__ float sigf(float x) {
    return __builtin_amdgcn_rcpf(1.0f + __builtin_amdgcn_exp2f(x * -1.44269504f));
}
// element (p) of an f32x4 pair-slot without dynamic vector indexing
__device__ __forceinline__ float sel2(f32x4 v, int p) {
    return p ? v[1] : v[0];   // rows {p, p+2} hold identical values; take p
}
// async global->LDS, 16B per lane (dest = wave-uniform base + lane*16)
__device__ __forceinline__ void gload_lds16(const void* g, void* l) {
    __builtin_amdgcn_global_load_lds(
        (const __attribute__((address_space(1))) void*)g,
        (__attribute__((address_space(3))) void*)l, 16, 0, 0);
}
// assemble i32x8 fragment from two 16B LDS chunks (compile-time indices only)
__device__ __forceinline__ i32x8 mk8(u32x4 lo, u32x4 hi) {
    i32x8 r;
    r[0] = (int)lo[0]; r[1] = (int)lo[1]; r[2] = (int)lo[2]; r[3] = (int)lo[3];
    r[4] = (int)hi[0]; r[5] = (int)hi[1]; r[6] = (int)hi[2]; r[7] = (int)hi[3];
    return r;
}

// ---------------- K0: merged prep (gather | Wx-T | Wd-T | Wh fp8) -----------
__global__ void k_prep_all(const int* __restrict__ tokens, const float* __restrict__ emb,
                           const float* __restrict__ Wx_f, const float* __restrict__ Wx_b,
                           const float* __restrict__ Wd,
                           const float* __restrict__ Wh_f, const float* __restrict__ Wh_b,
                           unsigned char* __restrict__ X8,
                           unsigned char* __restrict__ W8T,
                           unsigned short* __restrict__ WdT16,
                           unsigned char* __restrict__ WhP8) {
    int blk = blockIdx.x, k = threadIdx.x;           // k: 0..383
    if (blk < NROWS) {                               // gather: r = s*128 + b
        int b = blk & 127, s = blk >> 7;
        int tok = tokens[b * S_ + s];
        float v = (k < EMB_) ? emb[(long)tok * EMB_ + k] : 0.0f;
        X8[(long)blk * KP8 + k] = f2fp8(v);
    } else if (blk < NROWS + NCOLS) {                // Wx transpose -> fp8
        int c = blk - NROWS;
        float v = 0.0f;
        if (k < EMB_) v = (c < GF) ? Wx_f[k * GF + c] : Wx_b[k * GF + (c - GF)];
        W8T[(long)c * KP8 + k] = f2fp8(v);
    } else if (blk < NROWS + NCOLS + 86) {           // Wd transpose, flat
        int e = (blk - NROWS - NCOLS) * 384 + k;     // valid < 32768
        if (e < 64 * 512) {
            int c = e >> 9, kk = e & 511;
            float v = (c < TAGS_) ? Wd[kk * TAGS_ + c] : 0.0f;
            WdT16[c * 512 + kk] = f2bf(v);
        }
    } else if (k < 256) {                            // Wh -> fp8 (all gates)
        int row = blk - (NROWS + NCOLS + 86);        // 0..2047 = (d*4+gi)*256+j
        int d = row >> 10, rr = row & 1023, gi = rr >> 8, j = rr & 255;
        const float* Wh = d ? Wh_b : Wh_f;
        WhP8[(long)row * 256 + k] = f2fp8(Wh[k * GF + gi * HID_ + j]);
    }
}

// ---------------- K1: xz = X @ Wx + b  (fp8 MX-scaled MFMA, LDS-staged) -----
// Verified r9/r10. fp8 inputs + fp8 xz output (u32 packs the 4 batches of a
// group; same idx8 formula in u32 units). Byte-identical to r10.
__global__ __launch_bounds__(256) void k_gemm_xz(
    const unsigned char* __restrict__ X8, const unsigned char* __restrict__ W8T,
    const float* __restrict__ b_f, const float* __restrict__ b_b,
    unsigned int* __restrict__ xz32) {
    __shared__ __align__(16) unsigned char A8s[2][128 * 128];  // 2 x 16 KB
    __shared__ __align__(16) unsigned char B8s[2][128 * 128];  // 2 x 16 KB
    int w = threadIdx.x >> 6, lane = threadIdx.x & 63;
    int quad = lane >> 4, l16 = lane & 15;
    int m0 = blockIdx.x * 128;
    int n0 = blockIdx.y * 128;

    int rlane = lane >> 3;                 // 0..7 row within 8-row group
    int jpos  = lane & 7;                  // 16B-chunk position in LDS row
    int jsrc  = jpos ^ (rlane & 7);        // pre-swizzled source chunk

    f32x4 acc[2][8];
#pragma unroll
    for (int mt = 0; mt < 2; ++mt)
#pragma unroll
        for (int nt = 0; nt < 8; ++nt) acc[mt][nt] = (f32x4){0.f, 0.f, 0.f, 0.f};

#define STAGE(ST, BUFI) do {                                                    \
    int k0_ = (ST) * 128;                                                       \
    _Pragma("unroll")                                                           \
    for (int i_ = 0; i_ < 4; ++i_) {                                            \
        int rb_ = (w * 4 + i_) * 8;                                             \
        int r_  = rb_ + rlane;                                                  \
        gload_lds16(X8 + (long)(m0 + r_) * KP8 + k0_ + jsrc * 16,               \
                    &A8s[BUFI][rb_ * 128]);                                     \
    }                                                                           \
    _Pragma("unroll")                                                           \
    for (int i_ = 0; i_ < 4; ++i_) {                                            \
        int rb_ = (w * 4 + i_) * 8;                                             \
        int r_  = rb_ + rlane;                                                  \
        gload_lds16(W8T + (long)(n0 + r_) * KP8 + k0_ + jsrc * 16,              \
                    &B8s[BUFI][rb_ * 128]);                                     \
    }                                                                           \
} while (0)

    STAGE(0, 0);
    __syncthreads();
#pragma unroll
    for (int st = 0; st < 3; ++st) {       // 3 x K=128 = KP8 384
        if (st < 2) STAGE(st + 1, (st + 1) & 1);
        int bufi = st & 1;
        i32x8 a[2], bb[8];
#pragma unroll
        for (int mt = 0; mt < 2; ++mt) {
            int mrow = w * 32 + mt * 16 + l16;
            int x_ = mrow & 7;
            u32x4 lo = *reinterpret_cast<const u32x4*>(
                &A8s[bufi][mrow * 128 + ((2 * quad) ^ x_) * 16]);
            u32x4 hi = *reinterpret_cast<const u32x4*>(
                &A8s[bufi][mrow * 128 + ((2 * quad + 1) ^ x_) * 16]);
            a[mt] = mk8(lo, hi);
        }
#pragma unroll
        for (int nt = 0; nt < 8; ++nt) {
            int nrow = nt * 16 + l16;
            int x_ = nrow & 7;
            u32x4 lo = *reinterpret_cast<const u32x4*>(
                &B8s[bufi][nrow * 128 + ((2 * quad) ^ x_) * 16]);
            u32x4 hi = *reinterpret_cast<const u32x4*>(
                &B8s[bufi][nrow * 128 + ((2 * quad + 1) ^ x_) * 16]);
            bb[nt] = mk8(lo, hi);
        }
#pragma unroll
        for (int mt = 0; mt < 2; ++mt)
#pragma unroll
            for (int nt = 0; nt < 8; ++nt)
#if __has_builtin(__builtin_amdgcn_mfma_scale_f32_16x16x128_f8f6f4)
                acc[mt][nt] = __builtin_amdgcn_mfma_scale_f32_16x16x128_f8f6f4(
                    a[mt], bb[nt], acc[mt][nt], 0, 0, 0, 0x7F, 0, 0x7F);
#else
                acc[mt][nt] = acc[mt][nt];  // unreachable on gfx950
#endif
        __syncthreads();
    }
#undef STAGE

    int s = blockIdx.x;            // m>>7
#pragma unroll
    for (int mt = 0; mt < 2; ++mt) {
        int grp = w * 2 + mt;      // (b>>4)
#pragma unroll
        for (int nt = 0; nt < 8; ++nt) {
            int col = n0 + nt * 16 + l16;
            int dir = col >> 10, cc = col & 1023;
            int gate = cc >> 8, u16 = (cc & 255) >> 4;
            float bias = dir ? b_b[cc] : b_f[cc];
            // bytes 0..3 = batches r=0..3 (b = grp*16 + quad*4 + r)
            int t0 = __builtin_amdgcn_cvt_pk_fp8_f32(
                acc[mt][nt][0] + bias, acc[mt][nt][1] + bias, 0, false);
            int t1 = __builtin_amdgcn_cvt_pk_fp8_f32(
                acc[mt][nt][2] + bias, acc[mt][nt][3] + bias, t0, true);
            long idx8 = ((long)(s * 16 + dir * 8 + grp)) * 4096 +
                        (gate * 16 + u16) * 64 + quad * 16 + l16;
            xz32[idx8] = (unsigned int)t1;
        }
    }
}

// ---------------- K2: bidirectional LSTM recurrence, single-CU chains -------
// r3 structure + all-fp8 (verified r7-r10: 208-214us). Round-11 diffs:
//  - PAIR-COLOCATING block remap: bg2 and bg2^1 share xz8 cachelines (the
//    4-batch u32 groups); mapping them to the SAME XCD (x=blk&7) makes the
//    2nd read an L2 hit -> recurrence FETCH should drop 133 -> ~67 MB.
//  - incremental xz-prefetch pointer (+-262144 B/step, scalar-clamped at the
//    end) and hcat pointer (+-1024 B/step) replace per-step address math.
//  - hcat value via v_cvt_pk_bf16_f32 (1 op, RNE — replaces manual f2bf).
// Everything else byte-identical. step ~1950 cyc = 1104 MFMA + ~760 VALU.
__global__ __launch_bounds__(512, 2) void k_recurrence(
    const unsigned char* __restrict__ WhP8,
    const unsigned char* __restrict__ xz8, unsigned short* __restrict__ hcat16) {
    __shared__ __align__(16) unsigned char lds[1152];  // h8: 2 buf x 2 par x 288 B
    int tid = threadIdx.x;
    int w = tid >> 6, lane = tid & 63, quad = lane >> 4, l16 = lane & 15;
    // pair-colocating bijective remap: XCD x gets pairs {bg2, bg2^1}
    int blk = blockIdx.x;
    int x = blk & 7, rr_ = blk >> 3;             // rr_: 0..15
    int sub = rr_ & 1;
    int pid = x * 8 + (rr_ >> 1);                // 0..63 global pair id
    int d = pid >> 5, bg2 = ((pid & 31) << 1) | sub;
    int p = quad & 1;                            // lane's batch parity
    int cg = quad >> 1;                          // lane's colgroup (0/1)
    int col = 16 * (2 * w + cg) + l16;           // lane's cell column
    int rp = l16 & 1;                            // A-row parity of this lane's row

    // all-gate fp8 K=128 scaled-MFMA B fragments, register-pinned (128 VGPR)
    i32x8 wh8s[4][2][2];
#pragma unroll
    for (int gi = 0; gi < 4; ++gi)
#pragma unroll
        for (int cgi = 0; cgi < 2; ++cgi)
#pragma unroll
            for (int kt2 = 0; kt2 < 2; ++kt2) {
                const unsigned char* wp8 = WhP8 +
                    ((long)((d * 4 + gi) * 256 + 16 * (2 * w + cgi) + l16)) * 256 +
                    kt2 * 128 + quad * 32;
                i32x8 v = *reinterpret_cast<const i32x8*>(wp8);
                asm volatile("" : "+v"(v));
                wh8s[gi][cgi][kt2] = v;
            }

    float c2 = 0.f;

    // xz addressing (fp8): byte = (s*16+rowc)*16384 + ga*4096 + laneoff
    int rowc = d * 8 + (bg2 >> 3);
    unsigned int laneoff = (unsigned)((2 * w + cg) * 256 +
                                      (((bg2 >> 1) & 3) * 16 + l16) * 4 +
                                      2 * (bg2 & 1) + p);
    long step_xz = d ? -262144L : 262144L;       // per-s stride (16*16384 B)
    long step_hc = d ? -512L : 512L;             // per-s stride in shorts

    const unsigned char* xzp;                    // points at current prefetch tgt
    unsigned short* hcp;                         // this step's hcat store addr
    unsigned int xzu[4];
    {
        int s0 = d ? 255 : 0;
        xzp = xz8 + (unsigned long)(s0 * 16 + rowc) * 16384 + laneoff;
        hcp = hcat16 + ((long)(bg2 * 2 + p) * S_ + s0) * 512 + d * HID_ + col;
#pragma unroll
        for (int ga = 0; ga < 4; ++ga) xzu[ga] = xzp[ga * 4096];
    }

    for (int t = 0; t < 256; ++t) {
        int pb = t & 1, cb = pb ^ 1;
        f32x4 acc8[4][2];
#pragma unroll
        for (int gi = 0; gi < 4; ++gi)
#pragma unroll
            for (int cgi = 0; cgi < 2; ++cgi) acc8[gi][cgi] = (f32x4){0.f, 0.f, 0.f, 0.f};

        if (t > 0) {
#pragma unroll
            for (int kt2 = 0; kt2 < 2; ++kt2) {
                i32x8 A8 = *reinterpret_cast<const i32x8*>(
                    lds + cb * 576 + rp * 288 + kt2 * 128 + quad * 32);
#pragma unroll
                for (int cgi = 0; cgi < 2; ++cgi)
#pragma unroll
                    for (int gi = 0; gi < 4; ++gi)
#if __has_builtin(__builtin_amdgcn_mfma_scale_f32_16x16x128_f8f6f4)
                        acc8[gi][cgi] = __builtin_amdgcn_mfma_scale_f32_16x16x128_f8f6f4(
                            A8, wh8s[gi][cgi][kt2], acc8[gi][cgi], 0, 0, 0, 0x7F, 0, 0x7F);
#else
                        acc8[gi][cgi] = acc8[gi][cgi];  // unreachable on gfx950
#endif
            }
        }
        // extract current-step xz addends (fp8 -> f32, one cvt each)
        float xa0 = fp8_to_f32(xzu[0]);
        float xa1 = fp8_to_f32(xzu[1]);
        float xa2 = fp8_to_f32(xzu[2]);
        float xa3 = fp8_to_f32(xzu[3]);
        // advance prefetch pointer (scalar-clamped at the last step) + prefetch
        xzp += (t < 255) ? step_xz : 0L;
#pragma unroll
        for (int ga = 0; ga < 4; ++ga) xzu[ga] = xzp[ga * 4096];
        // gates: lane's cell (batch bg2*2+p, col). C row m=quad*4+r has batch
        // m&1=r&1 -> element p (== element p+2). Colgroup pick by cg.
        float zi = (cg ? sel2(acc8[0][1], p) : sel2(acc8[0][0], p)) + xa0;
        float zf = (cg ? sel2(acc8[1][1], p) : sel2(acc8[1][0], p)) + xa1;
        float zg = (cg ? sel2(acc8[2][1], p) : sel2(acc8[2][0], p)) + xa2;
        float zo = (cg ? sel2(acc8[3][1], p) : sel2(acc8[3][0], p)) + xa3;
        float c = sigf(zf) * c2 + sigf(zi) * fmaxf(zg, 0.0f);
        c2 = c;
        float h = sigf(zo) * fmaxf(c, 0.0f);

        int p8 = __builtin_amdgcn_cvt_pk_fp8_f32(h, h, 0, false);
        *(lds + pb * 576 + p * 288 + col) = (unsigned char)(p8 & 0xff);
        // hcat via packed bf16 cvt (RNE) + incremental pointer
        unsigned int hb;
        asm("v_cvt_pk_bf16_f32 %0, %1, %2" : "=v"(hb) : "v"(h), "v"(h));
        *hcp = (unsigned short)hb;
        hcp += step_hc;
        // LDS-only barrier: no vmcnt drain (global stores/loads stay in flight)
        asm volatile("s_waitcnt lgkmcnt(0)\n\ts_barrier" ::: "memory");
    }
}

// ---------------- K3: logits = hcat @ Wd, +bd, fused softmax -> out ---------
// LDS-staged (r8, verified). Unchanged.
__global__ __launch_bounds__(256) void k_gemm_logits(
    const unsigned short* __restrict__ hcat16, const unsigned short* __restrict__ WdT16,
    const float* __restrict__ bd, float* __restrict__ out) {
    __shared__ __align__(16) unsigned short Asw[2][128 * 64];  // 2 x 16 KB
    __shared__ __align__(16) unsigned short Bsw[2][64 * 64];   // 2 x 8 KB
    int w = threadIdx.x >> 6, lane = threadIdx.x & 63;
    int quad = lane >> 4, l16 = lane & 15;
    int m0 = blockIdx.x * 128;
    int rlane = lane >> 3, jpos = lane & 7;
    int jsrc = jpos ^ (rlane & 7);

    f32x4 acc[2][4];
#pragma unroll
    for (int mt = 0; mt < 2; ++mt)
#pragma unroll
        for (int nt = 0; nt < 4; ++nt) acc[mt][nt] = (f32x4){0.f, 0.f, 0.f, 0.f};

#define STAGE3(ST, BUFI) do {                                                   \
    int k0_ = (ST) * 64;                                                        \
    _Pragma("unroll")                                                           \
    for (int i_ = 0; i_ < 4; ++i_) {                                            \
        int rb_ = (w * 4 + i_) * 8;                                             \
        int r_  = rb_ + rlane;                                                  \
        gload_lds16(hcat16 + (long)(m0 + r_) * 512 + k0_ + jsrc * 8,            \
                    &Asw[BUFI][rb_ * 64]);                                      \
    }                                                                           \
    _Pragma("unroll")                                                           \
    for (int i_ = 0; i_ < 2; ++i_) {                                            \
        int rb_ = (w * 2 + i_) * 8;                                             \
        int r_  = rb_ + rlane;                                                  \
        gload_lds16(WdT16 + (long)r_ * 512 + k0_ + jsrc * 8,                    \
                    &Bsw[BUFI][rb_ * 64]);                                      \
    }                                                                           \
} while (0)

    STAGE3(0, 0);
    __syncthreads();
#pragma unroll
    for (int st = 0; st < 8; ++st) {       // 8 x BK=64 = K 512
        if (st < 7) STAGE3(st + 1, (st + 1) & 1);
        int bufi = st & 1;
#pragma unroll
        for (int ks = 0; ks < 2; ++ks) {
            bf16x8 a[2], bb[4];
#pragma unroll
            for (int mt = 0; mt < 2; ++mt) {
                int mrow = w * 32 + mt * 16 + l16;
                int jp = (ks * 4 + quad) ^ (l16 & 7);
                a[mt] = ldb8(&Asw[bufi][mrow * 64 + jp * 8]);
            }
#pragma unroll
            for (int nt = 0; nt < 4; ++nt) {
                int nrow = nt * 16 + l16;
                int jp = (ks * 4 + quad) ^ (l16 & 7);
                bb[nt] = ldb8(&Bsw[bufi][nrow * 64 + jp * 8]);
            }
#pragma unroll
            for (int mt = 0; mt < 2; ++mt)
#pragma unroll
                for (int nt = 0; nt < 4; ++nt)
                    acc[mt][nt] = __builtin_amdgcn_mfma_f32_16x16x32_bf16(a[mt], bb[nt], acc[mt][nt], 0, 0, 0);
        }
        __syncthreads();
    }
#undef STAGE3

#pragma unroll
    for (int mt = 0; mt < 2; ++mt) {
#pragma unroll
        for (int r = 0; r < 4; ++r) {
            int row = m0 + w * 32 + mt * 16 + quad * 4 + r;
            float vv[4];
            float mx = -3.0e38f;
#pragma unroll
            for (int nt = 0; nt < 4; ++nt) {
                int cl = nt * 16 + l16;
                float tv = (cl < TAGS_) ? (acc[mt][nt][r] + bd[cl]) : -3.0e38f;
                vv[nt] = tv;
                mx = fmaxf(mx, tv);
            }
#pragma unroll
            for (int off = 8; off >= 1; off >>= 1) mx = fmaxf(mx, __shfl_xor(mx, off, 64));
            float sum = 0.f;
#pragma unroll
            for (int nt = 0; nt < 4; ++nt) {
                int cl = nt * 16 + l16;
                float e = (cl < TAGS_) ? __expf(vv[nt] - mx) : 0.0f;
                vv[nt] = e;
                sum += e;
            }
#pragma unroll
            for (int off = 8; off >= 1; off >>= 1) sum += __shfl_xor(sum, off, 64);
            float rs = __builtin_amdgcn_rcpf(sum);
#pragma unroll
            for (int nt = 0; nt < 4; ++nt) {
                int cl = nt * 16 + l16;
                if (cl < TAGS_) out[(long)row * TAGS_ + cl] = vv[nt] * rs;
            }
        }
    }
}

extern "C" void kernel_launch(void* const* d_in, const int* in_sizes, int n_in,
                              void* d_out, int out_size, void* d_ws, size_t ws_size,
                              hipStream_t stream) {
    (void)in_sizes; (void)n_in; (void)out_size; (void)ws_size;
    const int*   tokens = (const int*)  d_in[0];
    const float* emb    = (const float*)d_in[1];
    const float* Wx_f   = (const float*)d_in[2];
    const float* Wh_f   = (const float*)d_in[3];
    const float* b_f    = (const float*)d_in[4];
    const float* Wx_b   = (const float*)d_in[5];
    const float* Wh_b   = (const float*)d_in[6];
    const float* b_b    = (const float*)d_in[7];
    const float* Wd     = (const float*)d_in[8];
    const float* bd     = (const float*)d_in[9];
    float* out = (float*)d_out;

    // workspace layout (bytes): total 190,119,936
    uint8_t* w = (uint8_t*)d_ws;
    unsigned char*  X8     = (unsigned char*)(w);                   // 12,582,912
    unsigned char*  W8T    = (unsigned char*)(w + 12582912);        //    786,432
    unsigned short* WdT16  = (unsigned short*)(w + 22282240);       //     65,536
    unsigned char*  xz8    = (unsigned char*)(w + 22347776);        // 67,108,864 (fp8)
    unsigned char*  WhP8   = (unsigned char*)(w + 89456640);        //    524,288 (no alias)
    unsigned short* hcat16 = (unsigned short*)(w + 156565504);      //  33,554,432

    // merged prep: gather (32768) | Wx-T (2048) | Wd-T (86) | Wh-fp8 (2048)
    k_prep_all  <<<dim3(NROWS + NCOLS + 86 + 2048), dim3(KP8), 0, stream>>>(
        tokens, emb, Wx_f, Wx_b, Wd, Wh_f, Wh_b, X8, W8T, WdT16, WhP8);
    k_gemm_xz   <<<dim3(256, 16),   dim3(256),  0, stream>>>(
        X8, W8T, b_f, b_b, (unsigned int*)xz8);
    k_recurrence<<<dim3(128),       dim3(512),  0, stream>>>(WhP8, xz8, hcat16);
    k_gemm_logits<<<dim3(256),      dim3(256),  0, stream>>>(hcat16, WdT16, bd, out);
}